// Round 10
// baseline (2249.336 us; speedup 1.0000x reference)
//
#include <hip/hip_runtime.h>
#include <hip/hip_fp16.h>
#include <math.h>

// ws float offsets
#define OFF_TOKPROJ 0         // 12288
#define OFF_FLAGS   12288     // 256 u32
#define OFF_VERDICT 12544     // 1 u32
#define OFF_PROBS   12548     // 256*256 u32 (per-4-row partial sums, q30)
#define OFF_SLOT2   78084     // 256*256 u32 (rare path, tagged q27 sums)
#define OFF_HH      143620    // 1024*256*64 fp16 = 8388608 f
// total = 8,532,228 floats = 34.13 MB  (<= proven ws >= 34.21 MB)

#define THRESH30 (512ULL << 30)
#define THRESH27 (512ULL << 27)
#define SPIN_BOUND (1 << 18)

__device__ __forceinline__ float sigf(float x) { return 1.f / (1.f + expf(-x)); }

// ---------------- prep: tokproj table + zero SLOT2 ----------------
__global__ __launch_bounds__(64) void prep_k(
    const float* __restrict__ embed, const float* __restrict__ gwih,
    const float* __restrict__ gbih, float* __restrict__ ws)
{
    int blk = blockIdx.x, l = threadIdx.x;
    if (blk < 64) {
        float* tokproj = ws + OFF_TOKPROJ;
        int v = blk;
        for (int j = l; j < 192; j += 64) {
            float s = gbih[j];
            for (int d = 0; d < 64; ++d) s += embed[v * 64 + d] * gwih[j * 128 + d];
            tokproj[v * 192 + j] = s;
        }
    } else {
        float* z = ws + OFF_SLOT2;
        int base = (blk - 64) * 4096;
        for (int i = base + l; i < base + 4096; i += 64) z[i] = 0.f;
    }
}

// ---------------- k1: GRU-only recurrence + fp16 history + logits ----------
__global__ __launch_bounds__(256, 1) void gru_k(
    const int* __restrict__ seq, const float* __restrict__ gwhh,
    const float* __restrict__ gbhh, const float* __restrict__ hw,
    const float* __restrict__ hb, float* __restrict__ ws,
    float* __restrict__ out)
{
    int tid = threadIdx.x, w = tid >> 6, l = tid & 63, b = blockIdx.x;
    int r = b * 4 + w;
    const float* tokproj = ws + OFF_TOKPROJ;
    __half* Hh = (__half*)(ws + OFF_HH);

    __shared__ float hs[4][64];
    __shared__ int toks[4][256];
    for (int k = 0; k < 4; ++k) toks[w][k * 64 + l] = seq[r * 256 + k * 64 + l];

    float wh0[64], wh1[64], wh2[64];
    #pragma unroll
    for (int d4 = 0; d4 < 16; ++d4) {
        float4 a0 = *(const float4*)(gwhh + (size_t)l * 64 + d4 * 4);
        float4 a1 = *(const float4*)(gwhh + (size_t)(64 + l) * 64 + d4 * 4);
        float4 a2 = *(const float4*)(gwhh + (size_t)(128 + l) * 64 + d4 * 4);
        wh0[d4*4] = a0.x; wh0[d4*4+1] = a0.y; wh0[d4*4+2] = a0.z; wh0[d4*4+3] = a0.w;
        wh1[d4*4] = a1.x; wh1[d4*4+1] = a1.y; wh1[d4*4+2] = a1.z; wh1[d4*4+3] = a1.w;
        wh2[d4*4] = a2.x; wh2[d4*4+1] = a2.y; wh2[d4*4+2] = a2.z; wh2[d4*4+3] = a2.w;
    }
    float g0b = gbhh[l], g1b = gbhh[64 + l], g2b = gbhh[128 + l];

    float h = 0.f;
    hs[w][l] = 0.f;
    int tok0 = toks[w][0];
    float gi0 = tokproj[tok0 * 192 + l], gi1 = tokproj[tok0 * 192 + 64 + l],
          gi2 = tokproj[tok0 * 192 + 128 + l];

    for (int t = 0; t < 256; ++t) {
        float ni0 = 0.f, ni1 = 0.f, ni2 = 0.f;
        if (t < 255) {
            int tk = toks[w][t + 1];
            ni0 = tokproj[tk * 192 + l];
            ni1 = tokproj[tk * 192 + 64 + l];
            ni2 = tokproj[tk * 192 + 128 + l];
        }
        float gh0 = g0b, gh1 = g1b, gh2 = g2b;
        #pragma unroll
        for (int d4 = 0; d4 < 16; ++d4) {
            float4 hv = *(const float4*)&hs[w][d4 * 4];
            gh0 += hv.x*wh0[d4*4] + hv.y*wh0[d4*4+1] + hv.z*wh0[d4*4+2] + hv.w*wh0[d4*4+3];
            gh1 += hv.x*wh1[d4*4] + hv.y*wh1[d4*4+1] + hv.z*wh1[d4*4+2] + hv.w*wh1[d4*4+3];
            gh2 += hv.x*wh2[d4*4] + hv.y*wh2[d4*4+1] + hv.z*wh2[d4*4+2] + hv.w*wh2[d4*4+3];
        }
        float r_ = sigf(gi0 + gh0), z_ = sigf(gi1 + gh1);
        float n_ = tanhf(gi2 + r_ * gh2);
        h = (1.f - z_) * n_ + z_ * h;
        hs[w][l] = h;
        Hh[((size_t)r * 256 + t) * 64 + l] = __float2half(h);
        gi0 = ni0; gi1 = ni1; gi2 = ni2;
    }

    // logits from exact h_255
    float sL = hb[l];
    #pragma unroll
    for (int d4 = 0; d4 < 16; ++d4) {
        float4 w4 = *(const float4*)(hw + (size_t)l * 64 + d4 * 4);
        float4 hv = *(const float4*)&hs[w][d4 * 4];
        sL += hv.x * w4.x + hv.y * w4.y + hv.z * w4.z + hv.w * w4.w;
    }
    out[r * 64 + l] = sL;
}

// ---------------- k2: all triggers in parallel ----------------
__global__ __launch_bounds__(256, 2) void trig_k(
    const float* __restrict__ lwih, const float* __restrict__ lwhh,
    const float* __restrict__ lbih, const float* __restrict__ lbhh,
    const float* __restrict__ tw, const float* __restrict__ tb,
    float* __restrict__ ws)
{
    int tid = threadIdx.x, w = tid >> 6, l = tid & 63, b = blockIdx.x;
    int rg = b >> 4, c = b & 15;
    int r = rg * 4 + w;
    int t0 = 3 + 16 * c;
    int ntrig = (c == 15) ? 13 : 16;
    int wlen = ntrig + 3;

    const __half* Hh = (const __half*)(ws + OFF_HH);
    unsigned int* PR = (unsigned int*)(ws + OFF_PROBS);

    __shared__ float hwin[4][19][64];
    __shared__ float pwin[4][19][128];
    __shared__ float hs2[4][32];
    __shared__ unsigned int probq[4][16];

    float wl0[64], wl1[64], lh0[32], lh1[32];
    #pragma unroll
    for (int d4 = 0; d4 < 16; ++d4) {
        float4 b0 = *(const float4*)(lwih + (size_t)l * 64 + d4 * 4);
        float4 b1 = *(const float4*)(lwih + (size_t)(64 + l) * 64 + d4 * 4);
        wl0[d4*4] = b0.x; wl0[d4*4+1] = b0.y; wl0[d4*4+2] = b0.z; wl0[d4*4+3] = b0.w;
        wl1[d4*4] = b1.x; wl1[d4*4+1] = b1.y; wl1[d4*4+2] = b1.z; wl1[d4*4+3] = b1.w;
    }
    #pragma unroll
    for (int d4 = 0; d4 < 8; ++d4) {
        float4 c0 = *(const float4*)(lwhh + (size_t)l * 32 + d4 * 4);
        float4 c1 = *(const float4*)(lwhh + (size_t)(64 + l) * 32 + d4 * 4);
        lh0[d4*4] = c0.x; lh0[d4*4+1] = c0.y; lh0[d4*4+2] = c0.z; lh0[d4*4+3] = c0.w;
        lh1[d4*4] = c1.x; lh1[d4*4+1] = c1.y; lh1[d4*4+2] = c1.z; lh1[d4*4+3] = c1.w;
    }
    float lb0 = lbih[l] + lbhh[l], lb1 = lbih[64 + l] + lbhh[64 + l];
    float twr = (l < 32) ? tw[l] : 0.f;
    float tb0 = tb[0];

    // stage fp16 h window -> fp32 LDS
    for (int i = 0; i < wlen; ++i)
        hwin[w][i][l] = __half2float(Hh[((size_t)r * 256 + (t0 - 3 + i)) * 64 + l]);

    // projections (shared across triggers)
    for (int i = 0; i < wlen; ++i) {
        float p0 = lb0, p1 = lb1;
        #pragma unroll
        for (int d4 = 0; d4 < 16; ++d4) {
            float4 hv = *(const float4*)&hwin[w][i][d4 * 4];
            p0 += hv.x*wl0[d4*4] + hv.y*wl0[d4*4+1] + hv.z*wl0[d4*4+2] + hv.w*wl0[d4*4+3];
            p1 += hv.x*wl1[d4*4] + hv.y*wl1[d4*4+1] + hv.z*wl1[d4*4+2] + hv.w*wl1[d4*4+3];
        }
        pwin[w][i][l] = p0; pwin[w][i][64 + l] = p1;
    }

    // triggers
    for (int j = 0; j < ntrig; ++j) {
        float hh = 0.f, cc = 0.f;
        #pragma unroll
        for (int k = 0; k < 4; ++k) {
            float q0 = pwin[w][j + k][l], q1 = pwin[w][j + k][64 + l];
            if (k) {
                #pragma unroll
                for (int d4 = 0; d4 < 8; ++d4) {
                    float4 hv = *(const float4*)&hs2[w][d4 * 4];
                    q0 += hv.x*lh0[d4*4] + hv.y*lh0[d4*4+1] + hv.z*lh0[d4*4+2] + hv.w*lh0[d4*4+3];
                    q1 += hv.x*lh1[d4*4] + hv.y*lh1[d4*4+1] + hv.z*lh1[d4*4+2] + hv.w*lh1[d4*4+3];
                }
            }
            float f_ = __shfl(q0, l + 32), o_ = __shfl(q1, l + 32);
            float ig = sigf(q0), ff = sigf(f_), gg = tanhf(q1), oo = sigf(o_);
            float ncc = ff * cc + ig * gg;
            float nhh = oo * tanhf(ncc);
            if (l < 32) { cc = ncc; hh = nhh; hs2[w][l] = nhh; }
        }
        float pp = (l < 32) ? hh * twr : 0.f;
        #pragma unroll
        for (int o = 32; o; o >>= 1) pp += __shfl_xor(pp, o);
        if (l == 0) {
            float prob = sigf(pp + tb0);
            unsigned long long q = (unsigned long long)llrint((double)prob * 1073741824.0);
            if (q > 0x3FFFFFFFull) q = 0x3FFFFFFFull;
            probq[w][j] = (unsigned int)q;
        }
    }
    __syncthreads();
    if (w == 0 && l < ntrig) {
        unsigned int s = probq[0][l] + probq[1][l] + probq[2][l] + probq[3][l];
        PR[(size_t)(t0 + l) * 256 + rg] = s;
    }
}

// ---------------- k3: flag reduction (one wave per t) ----------------
__global__ __launch_bounds__(256) void red_k(float* __restrict__ ws)
{
    int tid = threadIdx.x, w = tid >> 6, l = tid & 63;
    int t = 3 + blockIdx.x * 4 + w;
    if (t > 255) return;
    const unsigned int* PR = (const unsigned int*)(ws + OFF_PROBS);
    unsigned long long acc = 0;
    for (int k = 0; k < 4; ++k) acc += PR[(size_t)t * 256 + k * 64 + l];
    #pragma unroll
    for (int o = 32; o; o >>= 1) acc += __shfl_xor(acc, o);
    if (l == 0) ((unsigned int*)(ws + OFF_FLAGS))[t] = (acc > THRESH30) ? 1u : 0u;
}

// ---------------- k4: verdict ----------------
__global__ __launch_bounds__(64) void ver_k(float* __restrict__ ws, float* __restrict__ out)
{
    int l = threadIdx.x;
    const unsigned int* fl = (const unsigned int*)(ws + OFF_FLAGS);
    int mymin = 1 << 30, cnt = 0;
    for (int k = 0; k < 4; ++k) {
        int t = 3 + l + 64 * k;
        if (t <= 255) {
            unsigned int d = fl[t];
            cnt += (int)d;
            if (d && t < mymin) mymin = t;
        }
    }
    #pragma unroll
    for (int o = 32; o; o >>= 1) {
        mymin = min(mymin, __shfl_xor(mymin, o));
        cnt += __shfl_xor(cnt, o);
    }
    if (l == 0) {
        unsigned int* vd = (unsigned int*)(ws + OFF_VERDICT);
        if (mymin > 255) { vd[0] = 0u; out[65536] = 0.f; }
        else vd[0] = 1u | ((unsigned int)mymin << 8);
    }
}

// ---------------- k5: no-op on no-fire; full careful replay on fire --------
__global__ __launch_bounds__(256, 1) void fin_k(
    const int* __restrict__ seq, const float* __restrict__ memory,
    const float* __restrict__ gwih, const float* __restrict__ gwhh,
    const float* __restrict__ gbhh, const float* __restrict__ qw,
    const float* __restrict__ qb, const float* __restrict__ kw,
    const float* __restrict__ vw, const float* __restrict__ vb,
    const float* __restrict__ lwih, const float* __restrict__ lwhh,
    const float* __restrict__ lbih, const float* __restrict__ lbhh,
    const float* __restrict__ tw, const float* __restrict__ tb,
    const float* __restrict__ hw, const float* __restrict__ hb,
    float* __restrict__ ws, float* __restrict__ out)
{
    unsigned int vd = ((const unsigned int*)(ws + OFF_VERDICT))[0];
    if (!(vd & 1u)) return;     // common path: nothing to do
    int tc = (int)(vd >> 8);

    int tid = threadIdx.x, w = tid >> 6, l = tid & 63, b = blockIdx.x;
    int r = b * 4 + w;
    const float* tokproj = ws + OFF_TOKPROJ;
    unsigned int* S2 = (unsigned int*)(ws + OFF_SLOT2);

    __shared__ float hs[4][64], qs[4][64], us[4][64], rs[4][64];
    __shared__ float hs2f[4][32];
    __shared__ float PXl[4][4][128];
    __shared__ unsigned int probq[4];
    __shared__ int flagLds;
    __shared__ int toks[4][256];

    for (int k = 0; k < 4; ++k) toks[w][k * 64 + l] = seq[r * 256 + k * 64 + l];
    if (tid == 0) flagLds = 0;

    float wh0[64], wh1[64], wh2[64], wl0[64], wl1[64], lh0[32], lh1[32];
    #pragma unroll
    for (int d4 = 0; d4 < 16; ++d4) {
        float4 a0 = *(const float4*)(gwhh + (size_t)l * 64 + d4 * 4);
        float4 a1 = *(const float4*)(gwhh + (size_t)(64 + l) * 64 + d4 * 4);
        float4 a2 = *(const float4*)(gwhh + (size_t)(128 + l) * 64 + d4 * 4);
        float4 b0 = *(const float4*)(lwih + (size_t)l * 64 + d4 * 4);
        float4 b1 = *(const float4*)(lwih + (size_t)(64 + l) * 64 + d4 * 4);
        wh0[d4*4] = a0.x; wh0[d4*4+1] = a0.y; wh0[d4*4+2] = a0.z; wh0[d4*4+3] = a0.w;
        wh1[d4*4] = a1.x; wh1[d4*4+1] = a1.y; wh1[d4*4+2] = a1.z; wh1[d4*4+3] = a1.w;
        wh2[d4*4] = a2.x; wh2[d4*4+1] = a2.y; wh2[d4*4+2] = a2.z; wh2[d4*4+3] = a2.w;
        wl0[d4*4] = b0.x; wl0[d4*4+1] = b0.y; wl0[d4*4+2] = b0.z; wl0[d4*4+3] = b0.w;
        wl1[d4*4] = b1.x; wl1[d4*4+1] = b1.y; wl1[d4*4+2] = b1.z; wl1[d4*4+3] = b1.w;
    }
    #pragma unroll
    for (int d4 = 0; d4 < 8; ++d4) {
        float4 c0 = *(const float4*)(lwhh + (size_t)l * 32 + d4 * 4);
        float4 c1 = *(const float4*)(lwhh + (size_t)(64 + l) * 32 + d4 * 4);
        lh0[d4*4] = c0.x; lh0[d4*4+1] = c0.y; lh0[d4*4+2] = c0.z; lh0[d4*4+3] = c0.w;
        lh1[d4*4] = c1.x; lh1[d4*4+1] = c1.y; lh1[d4*4+2] = c1.z; lh1[d4*4+3] = c1.w;
    }
    float g0b = gbhh[l], g1b = gbhh[64 + l], g2b = gbhh[128 + l];
    float lb0 = lbih[l] + lbhh[l], lb1 = lbih[64 + l] + lbhh[64 + l];
    float twr = (l < 32) ? tw[l] : 0.f;
    float tb0 = tb[0];
    const float* mrow = memory + (size_t)r * 16384;

    float h = 0.f;
    hs[w][l] = 0.f;
    bool fire = false, brk = false;
    int cnt = 1;
    __syncthreads();

    for (int t = 0; t < 256; ++t) {
        int tok = toks[w][t];
        float gi0 = tokproj[tok * 192 + l], gi1 = tokproj[tok * 192 + 64 + l],
              gi2 = tokproj[tok * 192 + 128 + l];
        float gh0 = g0b, gh1 = g1b, gh2 = g2b;
        #pragma unroll
        for (int d4 = 0; d4 < 16; ++d4) {
            float4 hv = *(const float4*)&hs[w][d4 * 4];
            gh0 += hv.x*wh0[d4*4] + hv.y*wh0[d4*4+1] + hv.z*wh0[d4*4+2] + hv.w*wh0[d4*4+3];
            gh1 += hv.x*wh1[d4*4] + hv.y*wh1[d4*4+1] + hv.z*wh1[d4*4+2] + hv.w*wh1[d4*4+3];
            gh2 += hv.x*wh2[d4*4] + hv.y*wh2[d4*4+1] + hv.z*wh2[d4*4+2] + hv.w*wh2[d4*4+3];
        }
        if (fire) {
            // ---- unfused exact attention on h_{t-1} ----
            float q = qb[l];
            #pragma unroll
            for (int d4 = 0; d4 < 16; ++d4) {
                float4 q4 = *(const float4*)(qw + (size_t)l * 64 + d4 * 4);
                float4 hv = *(const float4*)&hs[w][d4 * 4];
                q += hv.x * q4.x + hv.y * q4.y + hv.z * q4.z + hv.w * q4.w;
            }
            qs[w][l] = q;
            float qk = 0.f;
            for (int e = 0; e < 64; ++e) qk += qs[w][e] * kw[(size_t)e * 64 + l];
            qk *= 0.125f;
            us[w][l] = qk;
            float sc[4];
            for (int k = 0; k < 4; ++k) {
                const float* mp = mrow + (size_t)(k * 64 + l) * 64;
                float s = 0.f;
                #pragma unroll
                for (int d4 = 0; d4 < 16; ++d4) {
                    float4 m4 = *(const float4*)(mp + d4 * 4);
                    float4 kv = *(const float4*)&us[w][d4 * 4];
                    s += m4.x * kv.x + m4.y * kv.y + m4.z * kv.z + m4.w * kv.w;
                }
                sc[k] = s;
            }
            float mx = fmaxf(fmaxf(sc[0], sc[1]), fmaxf(sc[2], sc[3]));
            for (int o = 32; o; o >>= 1) mx = fmaxf(mx, __shfl_xor(mx, o));
            float den = 0.f;
            #pragma unroll
            for (int k = 0; k < 4; ++k) { sc[k] = expf(sc[k] - mx); den += sc[k]; }
            for (int o = 32; o; o >>= 1) den += __shfl_xor(den, o);
            float u = 0.f;
            for (int m = 0; m < 256; ++m) {
                float wm = __shfl(sc[m >> 6], m & 63);
                u += wm * mrow[(size_t)m * 64 + l];
            }
            u /= den;
            us[w][l] = u;
            float ret = vb[l];
            #pragma unroll
            for (int d4 = 0; d4 < 16; ++d4) {
                float4 v4 = *(const float4*)(vw + (size_t)l * 64 + d4 * 4);
                float4 uv = *(const float4*)&us[w][d4 * 4];
                ret += uv.x * v4.x + uv.y * v4.y + uv.z * v4.z + uv.w * v4.w;
            }
            rs[w][l] = ret;
            for (int e = 0; e < 64; ++e) {
                float re = rs[w][e];
                gi0 += re * gwih[(size_t)l * 128 + 64 + e];
                gi1 += re * gwih[(size_t)(64 + l) * 128 + 64 + e];
                gi2 += re * gwih[(size_t)(128 + l) * 128 + 64 + e];
            }
        }
        fire = false;
        float r_ = sigf(gi0 + gh0), z_ = sigf(gi1 + gh1);
        float n_ = tanhf(gi2 + r_ * gh2);
        h = (1.f - z_) * n_ + z_ * h;
        hs[w][l] = h;

        float p0 = lb0, p1 = lb1;
        #pragma unroll
        for (int d4 = 0; d4 < 16; ++d4) {
            float4 hv = *(const float4*)&hs[w][d4 * 4];
            p0 += hv.x*wl0[d4*4] + hv.y*wl0[d4*4+1] + hv.z*wl0[d4*4+2] + hv.w*wl0[d4*4+3];
            p1 += hv.x*wl1[d4*4] + hv.y*wl1[d4*4+1] + hv.z*wl1[d4*4+2] + hv.w*wl1[d4*4+3];
        }
        PXl[w][t & 3][l] = p0; PXl[w][t & 3][64 + l] = p1;

        if (t == tc) {
            fire = true;
        } else if (t > tc) {
            float hh = 0.f, cc = 0.f;
            #pragma unroll
            for (int k = 0; k < 4; ++k) {
                int s2 = (t - 3 + k) & 3;
                float q0 = PXl[w][s2][l], q1 = PXl[w][s2][64 + l];
                if (k) {
                    #pragma unroll
                    for (int d4 = 0; d4 < 8; ++d4) {
                        float4 hv = *(const float4*)&hs2f[w][d4 * 4];
                        q0 += hv.x*lh0[d4*4] + hv.y*lh0[d4*4+1] + hv.z*lh0[d4*4+2] + hv.w*lh0[d4*4+3];
                        q1 += hv.x*lh1[d4*4] + hv.y*lh1[d4*4+1] + hv.z*lh1[d4*4+2] + hv.w*lh1[d4*4+3];
                    }
                }
                float f_ = __shfl(q0, l + 32), o_ = __shfl(q1, l + 32);
                float ig = sigf(q0), ff = sigf(f_), gg = tanhf(q1), oo = sigf(o_);
                float ncc = ff * cc + ig * gg;
                float nhh = oo * tanhf(ncc);
                if (l < 32) { cc = ncc; hh = nhh; hs2f[w][l] = nhh; }
            }
            float pp = (l < 32) ? hh * twr : 0.f;
            #pragma unroll
            for (int o = 32; o; o >>= 1) pp += __shfl_xor(pp, o);
            if (l == 0) {
                float prob = sigf(pp + tb0);
                unsigned long long q = (unsigned long long)llrint((double)prob * 134217728.0);
                if (q > 0x7FFFFFFull) q = 0x7FFFFFFull;
                probq[w] = (unsigned int)q;
            }
            __syncthreads();
            if (w == 0 && l == 0) {
                unsigned int s = probq[0] + probq[1] + probq[2] + probq[3];
                __hip_atomic_store(&S2[(size_t)t * 256 + b], (1u << 30) | s,
                                   __ATOMIC_RELAXED, __HIP_MEMORY_SCOPE_AGENT);
            }
            if (w == 0) {
                unsigned long long tot = 0; int spin = 0; bool ok = true;
                if (!brk) {
                    for (;;) {
                        bool all4 = true; tot = 0;
                        #pragma unroll
                        for (int k2 = 0; k2 < 4; ++k2) {
                            unsigned int v = __hip_atomic_load(&S2[(size_t)t * 256 + k2 * 64 + l],
                                                               __ATOMIC_RELAXED, __HIP_MEMORY_SCOPE_AGENT);
                            all4 &= ((v >> 30) == 1u);
                            tot += (v & 0x3FFFFFFFu);
                        }
                        if (__all(all4)) break;
                        if (++spin > SPIN_BOUND) { ok = false; brk = true; break; }
                        __builtin_amdgcn_s_sleep(1);
                    }
                } else ok = false;
                #pragma unroll
                for (int o = 32; o; o >>= 1) tot += __shfl_xor(tot, o);
                int dec = (ok && tot > THRESH27) ? 1 : 0;
                cnt += dec;
                if (l == 0) flagLds = dec;
            }
            __syncthreads();
            fire = (flagLds != 0);
        }
    }

    // overwrite logits from exact replayed h
    float sL = hb[l];
    #pragma unroll
    for (int d4 = 0; d4 < 16; ++d4) {
        float4 w4 = *(const float4*)(hw + (size_t)l * 64 + d4 * 4);
        float4 hv = *(const float4*)&hs[w][d4 * 4];
        sL += hv.x * w4.x + hv.y * w4.y + hv.z * w4.z + hv.w * w4.w;
    }
    out[r * 64 + l] = sL;
    if (b == 0 && w == 0 && l == 0)
        out[65536] = brk ? -1234.f : (float)cnt / 256.f;
}

extern "C" void kernel_launch(void* const* d_in, const int* in_sizes, int n_in,
                              void* d_out, int out_size, void* d_ws, size_t ws_size,
                              hipStream_t stream)
{
    const int*   seq    = (const int*)d_in[0];
    const float* memory = (const float*)d_in[1];
    const float* embed  = (const float*)d_in[2];
    const float* gwih   = (const float*)d_in[3];
    const float* gwhh   = (const float*)d_in[4];
    const float* gbih   = (const float*)d_in[5];
    const float* gbhh   = (const float*)d_in[6];
    const float* qw     = (const float*)d_in[7];
    const float* qb     = (const float*)d_in[8];
    const float* kw     = (const float*)d_in[9];
    // d_in[10] = k_b : cancels in softmax, unused
    const float* vw     = (const float*)d_in[11];
    const float* vb     = (const float*)d_in[12];
    const float* lwih   = (const float*)d_in[13];
    const float* lwhh   = (const float*)d_in[14];
    const float* lbih   = (const float*)d_in[15];
    const float* lbhh   = (const float*)d_in[16];
    const float* tw     = (const float*)d_in[17];
    const float* tb     = (const float*)d_in[18];
    const float* hw     = (const float*)d_in[19];
    const float* hb     = (const float*)d_in[20];
    float* ws = (float*)d_ws;
    float* out = (float*)d_out;

    prep_k<<<80, 64, 0, stream>>>(embed, gwih, gbih, ws);
    gru_k<<<256, 256, 0, stream>>>(seq, gwhh, gbhh, hw, hb, ws, out);
    trig_k<<<4096, 256, 0, stream>>>(lwih, lwhh, lbih, lbhh, tw, tb, ws);
    red_k<<<64, 256, 0, stream>>>(ws);
    ver_k<<<1, 64, 0, stream>>>(ws, out);
    fin_k<<<256, 256, 0, stream>>>(seq, memory, gwih, gwhh, gbhh, qw, qb, kw,
                                   vw, vb, lwih, lwhh, lbih, lbhh, tw, tb,
                                   hw, hb, ws, out);
}

// Round 11
// 1096.595 us; speedup vs baseline: 2.0512x; 2.0512x over previous
//
#include <hip/hip_runtime.h>
#include <hip/hip_fp16.h>
#include <math.h>

// ws float offsets
#define OFF_TOKPROJ 0         // 12288
#define OFF_FLAGS   12288     // 256 u32
#define OFF_VERDICT 12544     // (unused)
#define OFF_PROBS   12548     // 256*256 u32 (per-4-row partial sums, q30)
#define OFF_SLOT2   78084     // 256*256 u32 (rare path, tagged q27 sums)
#define OFF_HH      143620    // 1024*256*64 fp16 = 8388608 f
// total = 8,532,228 floats = 34.13 MB

#define THRESH30 (512ULL << 30)
#define THRESH27 (512ULL << 27)
#define SPIN_BOUND (1 << 18)

__device__ __forceinline__ float sigf(float x) { return 1.f / (1.f + expf(-x)); }

// ---------------- prep: tokproj table + zero SLOT2 ----------------
__global__ __launch_bounds__(64) void prep_k(
    const float* __restrict__ embed, const float* __restrict__ gwih,
    const float* __restrict__ gbih, float* __restrict__ ws)
{
    int blk = blockIdx.x, l = threadIdx.x;
    if (blk < 64) {
        float* tokproj = ws + OFF_TOKPROJ;
        int v = blk;
        for (int j = l; j < 192; j += 64) {
            float s = gbih[j];
            for (int d = 0; d < 64; ++d) s += embed[v * 64 + d] * gwih[j * 128 + d];
            tokproj[v * 192 + j] = s;
        }
    } else {
        float* z = ws + OFF_SLOT2;
        int base = (blk - 64) * 4096;
        for (int i = base + l; i < base + 4096; i += 64) z[i] = 0.f;
    }
}

// ---------------- k1: GRU-only recurrence + fp16 history + logits ----------
__global__ __launch_bounds__(256, 1) void gru_k(
    const int* __restrict__ seq, const float* __restrict__ gwhh,
    const float* __restrict__ gbhh, const float* __restrict__ hw,
    const float* __restrict__ hb, float* __restrict__ ws,
    float* __restrict__ out)
{
    int tid = threadIdx.x, w = tid >> 6, l = tid & 63, b = blockIdx.x;
    int r = b * 4 + w;
    const float* tokproj = ws + OFF_TOKPROJ;
    __half* Hh = (__half*)(ws + OFF_HH);

    __shared__ float hs[4][64];
    __shared__ int toks[4][256];
    for (int k = 0; k < 4; ++k) toks[w][k * 64 + l] = seq[r * 256 + k * 64 + l];

    float wh0[64], wh1[64], wh2[64];
    #pragma unroll
    for (int d4 = 0; d4 < 16; ++d4) {
        float4 a0 = *(const float4*)(gwhh + (size_t)l * 64 + d4 * 4);
        float4 a1 = *(const float4*)(gwhh + (size_t)(64 + l) * 64 + d4 * 4);
        float4 a2 = *(const float4*)(gwhh + (size_t)(128 + l) * 64 + d4 * 4);
        wh0[d4*4] = a0.x; wh0[d4*4+1] = a0.y; wh0[d4*4+2] = a0.z; wh0[d4*4+3] = a0.w;
        wh1[d4*4] = a1.x; wh1[d4*4+1] = a1.y; wh1[d4*4+2] = a1.z; wh1[d4*4+3] = a1.w;
        wh2[d4*4] = a2.x; wh2[d4*4+1] = a2.y; wh2[d4*4+2] = a2.z; wh2[d4*4+3] = a2.w;
    }
    float g0b = gbhh[l], g1b = gbhh[64 + l], g2b = gbhh[128 + l];

    float h = 0.f;
    hs[w][l] = 0.f;
    int tok0 = toks[w][0];
    float gi0 = tokproj[tok0 * 192 + l], gi1 = tokproj[tok0 * 192 + 64 + l],
          gi2 = tokproj[tok0 * 192 + 128 + l];

    for (int t = 0; t < 256; ++t) {
        float ni0 = 0.f, ni1 = 0.f, ni2 = 0.f;
        if (t < 255) {
            int tk = toks[w][t + 1];
            ni0 = tokproj[tk * 192 + l];
            ni1 = tokproj[tk * 192 + 64 + l];
            ni2 = tokproj[tk * 192 + 128 + l];
        }
        float gh0 = g0b, gh1 = g1b, gh2 = g2b;
        #pragma unroll
        for (int d4 = 0; d4 < 16; ++d4) {
            float4 hv = *(const float4*)&hs[w][d4 * 4];
            gh0 += hv.x*wh0[d4*4] + hv.y*wh0[d4*4+1] + hv.z*wh0[d4*4+2] + hv.w*wh0[d4*4+3];
            gh1 += hv.x*wh1[d4*4] + hv.y*wh1[d4*4+1] + hv.z*wh1[d4*4+2] + hv.w*wh1[d4*4+3];
            gh2 += hv.x*wh2[d4*4] + hv.y*wh2[d4*4+1] + hv.z*wh2[d4*4+2] + hv.w*wh2[d4*4+3];
        }
        float r_ = sigf(gi0 + gh0), z_ = sigf(gi1 + gh1);
        float n_ = tanhf(gi2 + r_ * gh2);
        h = (1.f - z_) * n_ + z_ * h;
        hs[w][l] = h;
        Hh[((size_t)r * 256 + t) * 64 + l] = __float2half(h);
        gi0 = ni0; gi1 = ni1; gi2 = ni2;
    }

    // logits from exact h_255
    float sL = hb[l];
    #pragma unroll
    for (int d4 = 0; d4 < 16; ++d4) {
        float4 w4 = *(const float4*)(hw + (size_t)l * 64 + d4 * 4);
        float4 hv = *(const float4*)&hs[w][d4 * 4];
        sL += hv.x * w4.x + hv.y * w4.y + hv.z * w4.z + hv.w * w4.w;
    }
    out[r * 64 + l] = sL;
}

// ---------------- k2: all triggers in parallel (1 wave/SIMD, no spill) -----
__global__ __launch_bounds__(256, 1) void trig_k(
    const float* __restrict__ lwih, const float* __restrict__ lwhh,
    const float* __restrict__ lbih, const float* __restrict__ lbhh,
    const float* __restrict__ tw, const float* __restrict__ tb,
    float* __restrict__ ws)
{
    int tid = threadIdx.x, w = tid >> 6, l = tid & 63, b = blockIdx.x;
    int rg = b >> 4, c = b & 15;
    int r = rg * 4 + w;
    int t0 = 3 + 16 * c;
    int ntrig = (c == 15) ? 13 : 16;
    int wlen = ntrig + 3;

    const __half* Hh = (const __half*)(ws + OFF_HH);
    unsigned int* PR = (unsigned int*)(ws + OFF_PROBS);

    __shared__ float hwin[4][19][64];
    __shared__ float pwin[4][19][128];
    __shared__ float hs2[4][32];
    __shared__ unsigned int probq[4][16];

    float wl0[64], wl1[64], lh0[32], lh1[32];
    #pragma unroll
    for (int d4 = 0; d4 < 16; ++d4) {
        float4 b0 = *(const float4*)(lwih + (size_t)l * 64 + d4 * 4);
        float4 b1 = *(const float4*)(lwih + (size_t)(64 + l) * 64 + d4 * 4);
        wl0[d4*4] = b0.x; wl0[d4*4+1] = b0.y; wl0[d4*4+2] = b0.z; wl0[d4*4+3] = b0.w;
        wl1[d4*4] = b1.x; wl1[d4*4+1] = b1.y; wl1[d4*4+2] = b1.z; wl1[d4*4+3] = b1.w;
    }
    #pragma unroll
    for (int d4 = 0; d4 < 8; ++d4) {
        float4 c0 = *(const float4*)(lwhh + (size_t)l * 32 + d4 * 4);
        float4 c1 = *(const float4*)(lwhh + (size_t)(64 + l) * 32 + d4 * 4);
        lh0[d4*4] = c0.x; lh0[d4*4+1] = c0.y; lh0[d4*4+2] = c0.z; lh0[d4*4+3] = c0.w;
        lh1[d4*4] = c1.x; lh1[d4*4+1] = c1.y; lh1[d4*4+2] = c1.z; lh1[d4*4+3] = c1.w;
    }
    float lb0 = lbih[l] + lbhh[l], lb1 = lbih[64 + l] + lbhh[64 + l];
    float twr = (l < 32) ? tw[l] : 0.f;
    float tb0 = tb[0];

    // stage fp16 h window -> fp32 LDS
    for (int i = 0; i < wlen; ++i)
        hwin[w][i][l] = __half2float(Hh[((size_t)r * 256 + (t0 - 3 + i)) * 64 + l]);

    // projections (shared across triggers)
    for (int i = 0; i < wlen; ++i) {
        float p0 = lb0, p1 = lb1;
        #pragma unroll
        for (int d4 = 0; d4 < 16; ++d4) {
            float4 hv = *(const float4*)&hwin[w][i][d4 * 4];
            p0 += hv.x*wl0[d4*4] + hv.y*wl0[d4*4+1] + hv.z*wl0[d4*4+2] + hv.w*wl0[d4*4+3];
            p1 += hv.x*wl1[d4*4] + hv.y*wl1[d4*4+1] + hv.z*wl1[d4*4+2] + hv.w*wl1[d4*4+3];
        }
        pwin[w][i][l] = p0; pwin[w][i][64 + l] = p1;
    }

    // triggers
    for (int j = 0; j < ntrig; ++j) {
        float hh = 0.f, cc = 0.f;
        #pragma unroll
        for (int k = 0; k < 4; ++k) {
            float q0 = pwin[w][j + k][l], q1 = pwin[w][j + k][64 + l];
            if (k) {
                #pragma unroll
                for (int d4 = 0; d4 < 8; ++d4) {
                    float4 hv = *(const float4*)&hs2[w][d4 * 4];
                    q0 += hv.x*lh0[d4*4] + hv.y*lh0[d4*4+1] + hv.z*lh0[d4*4+2] + hv.w*lh0[d4*4+3];
                    q1 += hv.x*lh1[d4*4] + hv.y*lh1[d4*4+1] + hv.z*lh1[d4*4+2] + hv.w*lh1[d4*4+3];
                }
            }
            float f_ = __shfl(q0, l + 32), o_ = __shfl(q1, l + 32);
            float ig = sigf(q0), ff = sigf(f_), gg = tanhf(q1), oo = sigf(o_);
            float ncc = ff * cc + ig * gg;
            float nhh = oo * tanhf(ncc);
            if (l < 32) { cc = ncc; hh = nhh; hs2[w][l] = nhh; }
        }
        float pp = (l < 32) ? hh * twr : 0.f;
        #pragma unroll
        for (int o = 32; o; o >>= 1) pp += __shfl_xor(pp, o);
        if (l == 0) {
            float prob = sigf(pp + tb0);
            unsigned long long q = (unsigned long long)llrint((double)prob * 1073741824.0);
            if (q > 0x3FFFFFFFull) q = 0x3FFFFFFFull;
            probq[w][j] = (unsigned int)q;
        }
    }
    __syncthreads();
    if (w == 0 && l < ntrig) {
        unsigned int s = probq[0][l] + probq[1][l] + probq[2][l] + probq[3][l];
        PR[(size_t)(t0 + l) * 256 + rg] = s;
    }
}

// ---------------- k3: flag reduction (one wave per t) ----------------
__global__ __launch_bounds__(256) void red_k(float* __restrict__ ws)
{
    int tid = threadIdx.x, w = tid >> 6, l = tid & 63;
    int t = 3 + blockIdx.x * 4 + w;
    if (t > 255) return;
    const unsigned int* PR = (const unsigned int*)(ws + OFF_PROBS);
    unsigned long long acc = 0;
    for (int k = 0; k < 4; ++k) acc += PR[(size_t)t * 256 + k * 64 + l];
    #pragma unroll
    for (int o = 32; o; o >>= 1) acc += __shfl_xor(acc, o);
    if (l == 0) ((unsigned int*)(ws + OFF_FLAGS))[t] = (acc > THRESH30) ? 1u : 0u;
}

// ---------------- k4: inline verdict; no-op on no-fire; replay on fire -----
__global__ __launch_bounds__(256, 1) void fin_k(
    const int* __restrict__ seq, const float* __restrict__ memory,
    const float* __restrict__ gwih, const float* __restrict__ gwhh,
    const float* __restrict__ gbhh, const float* __restrict__ qw,
    const float* __restrict__ qb, const float* __restrict__ kw,
    const float* __restrict__ vw, const float* __restrict__ vb,
    const float* __restrict__ lwih, const float* __restrict__ lwhh,
    const float* __restrict__ lbih, const float* __restrict__ lbhh,
    const float* __restrict__ tw, const float* __restrict__ tb,
    const float* __restrict__ hw, const float* __restrict__ hb,
    float* __restrict__ ws, float* __restrict__ out)
{
    int tid = threadIdx.x, w = tid >> 6, l = tid & 63, b = blockIdx.x;

    // ---- inline verdict from flags ----
    __shared__ int redmin[4];
    {
        const unsigned int* fl = (const unsigned int*)(ws + OFF_FLAGS);
        int mymin = 1 << 30;
        if (tid >= 3 && fl[tid]) mymin = tid;
        #pragma unroll
        for (int o = 32; o; o >>= 1) mymin = min(mymin, __shfl_xor(mymin, o));
        if (l == 0) redmin[w] = mymin;
    }
    __syncthreads();
    int tc = min(min(redmin[0], redmin[1]), min(redmin[2], redmin[3]));
    if (tc > 255) {
        if (b == 0 && tid == 0) out[65536] = 0.f;
        return;                         // common path
    }

    int r = b * 4 + w;
    const float* tokproj = ws + OFF_TOKPROJ;
    unsigned int* S2 = (unsigned int*)(ws + OFF_SLOT2);

    __shared__ float hs[4][64], qs[4][64], us[4][64], rs[4][64];
    __shared__ float hs2f[4][32];
    __shared__ float PXl[4][4][128];
    __shared__ unsigned int probq[4];
    __shared__ int flagLds;
    __shared__ int toks[4][256];

    for (int k = 0; k < 4; ++k) toks[w][k * 64 + l] = seq[r * 256 + k * 64 + l];
    if (tid == 0) flagLds = 0;

    float wh0[64], wh1[64], wh2[64], wl0[64], wl1[64], lh0[32], lh1[32];
    #pragma unroll
    for (int d4 = 0; d4 < 16; ++d4) {
        float4 a0 = *(const float4*)(gwhh + (size_t)l * 64 + d4 * 4);
        float4 a1 = *(const float4*)(gwhh + (size_t)(64 + l) * 64 + d4 * 4);
        float4 a2 = *(const float4*)(gwhh + (size_t)(128 + l) * 64 + d4 * 4);
        float4 b0 = *(const float4*)(lwih + (size_t)l * 64 + d4 * 4);
        float4 b1 = *(const float4*)(lwih + (size_t)(64 + l) * 64 + d4 * 4);
        wh0[d4*4] = a0.x; wh0[d4*4+1] = a0.y; wh0[d4*4+2] = a0.z; wh0[d4*4+3] = a0.w;
        wh1[d4*4] = a1.x; wh1[d4*4+1] = a1.y; wh1[d4*4+2] = a1.z; wh1[d4*4+3] = a1.w;
        wh2[d4*4] = a2.x; wh2[d4*4+1] = a2.y; wh2[d4*4+2] = a2.z; wh2[d4*4+3] = a2.w;
        wl0[d4*4] = b0.x; wl0[d4*4+1] = b0.y; wl0[d4*4+2] = b0.z; wl0[d4*4+3] = b0.w;
        wl1[d4*4] = b1.x; wl1[d4*4+1] = b1.y; wl1[d4*4+2] = b1.z; wl1[d4*4+3] = b1.w;
    }
    #pragma unroll
    for (int d4 = 0; d4 < 8; ++d4) {
        float4 c0 = *(const float4*)(lwhh + (size_t)l * 32 + d4 * 4);
        float4 c1 = *(const float4*)(lwhh + (size_t)(64 + l) * 32 + d4 * 4);
        lh0[d4*4] = c0.x; lh0[d4*4+1] = c0.y; lh0[d4*4+2] = c0.z; lh0[d4*4+3] = c0.w;
        lh1[d4*4] = c1.x; lh1[d4*4+1] = c1.y; lh1[d4*4+2] = c1.z; lh1[d4*4+3] = c1.w;
    }
    float g0b = gbhh[l], g1b = gbhh[64 + l], g2b = gbhh[128 + l];
    float lb0 = lbih[l] + lbhh[l], lb1 = lbih[64 + l] + lbhh[64 + l];
    float twr = (l < 32) ? tw[l] : 0.f;
    float tb0 = tb[0];
    const float* mrow = memory + (size_t)r * 16384;

    float h = 0.f;
    hs[w][l] = 0.f;
    bool fire = false, brk = false;
    int cnt = 1;
    __syncthreads();

    for (int t = 0; t < 256; ++t) {
        int tok = toks[w][t];
        float gi0 = tokproj[tok * 192 + l], gi1 = tokproj[tok * 192 + 64 + l],
              gi2 = tokproj[tok * 192 + 128 + l];
        float gh0 = g0b, gh1 = g1b, gh2 = g2b;
        #pragma unroll
        for (int d4 = 0; d4 < 16; ++d4) {
            float4 hv = *(const float4*)&hs[w][d4 * 4];
            gh0 += hv.x*wh0[d4*4] + hv.y*wh0[d4*4+1] + hv.z*wh0[d4*4+2] + hv.w*wh0[d4*4+3];
            gh1 += hv.x*wh1[d4*4] + hv.y*wh1[d4*4+1] + hv.z*wh1[d4*4+2] + hv.w*wh1[d4*4+3];
            gh2 += hv.x*wh2[d4*4] + hv.y*wh2[d4*4+1] + hv.z*wh2[d4*4+2] + hv.w*wh2[d4*4+3];
        }
        if (fire) {
            // ---- unfused exact attention on h_{t-1} ----
            float q = qb[l];
            #pragma unroll
            for (int d4 = 0; d4 < 16; ++d4) {
                float4 q4 = *(const float4*)(qw + (size_t)l * 64 + d4 * 4);
                float4 hv = *(const float4*)&hs[w][d4 * 4];
                q += hv.x * q4.x + hv.y * q4.y + hv.z * q4.z + hv.w * q4.w;
            }
            qs[w][l] = q;
            float qk = 0.f;
            for (int e = 0; e < 64; ++e) qk += qs[w][e] * kw[(size_t)e * 64 + l];
            qk *= 0.125f;
            us[w][l] = qk;
            float sc[4];
            for (int k = 0; k < 4; ++k) {
                const float* mp = mrow + (size_t)(k * 64 + l) * 64;
                float s = 0.f;
                #pragma unroll
                for (int d4 = 0; d4 < 16; ++d4) {
                    float4 m4 = *(const float4*)(mp + d4 * 4);
                    float4 kv = *(const float4*)&us[w][d4 * 4];
                    s += m4.x * kv.x + m4.y * kv.y + m4.z * kv.z + m4.w * kv.w;
                }
                sc[k] = s;
            }
            float mx = fmaxf(fmaxf(sc[0], sc[1]), fmaxf(sc[2], sc[3]));
            for (int o = 32; o; o >>= 1) mx = fmaxf(mx, __shfl_xor(mx, o));
            float den = 0.f;
            #pragma unroll
            for (int k = 0; k < 4; ++k) { sc[k] = expf(sc[k] - mx); den += sc[k]; }
            for (int o = 32; o; o >>= 1) den += __shfl_xor(den, o);
            float u = 0.f;
            for (int m = 0; m < 256; ++m) {
                float wm = __shfl(sc[m >> 6], m & 63);
                u += wm * mrow[(size_t)m * 64 + l];
            }
            u /= den;
            us[w][l] = u;
            float ret = vb[l];
            #pragma unroll
            for (int d4 = 0; d4 < 16; ++d4) {
                float4 v4 = *(const float4*)(vw + (size_t)l * 64 + d4 * 4);
                float4 uv = *(const float4*)&us[w][d4 * 4];
                ret += uv.x * v4.x + uv.y * v4.y + uv.z * v4.z + uv.w * v4.w;
            }
            rs[w][l] = ret;
            for (int e = 0; e < 64; ++e) {
                float re = rs[w][e];
                gi0 += re * gwih[(size_t)l * 128 + 64 + e];
                gi1 += re * gwih[(size_t)(64 + l) * 128 + 64 + e];
                gi2 += re * gwih[(size_t)(128 + l) * 128 + 64 + e];
            }
        }
        fire = false;
        float r_ = sigf(gi0 + gh0), z_ = sigf(gi1 + gh1);
        float n_ = tanhf(gi2 + r_ * gh2);
        h = (1.f - z_) * n_ + z_ * h;
        hs[w][l] = h;

        float p0 = lb0, p1 = lb1;
        #pragma unroll
        for (int d4 = 0; d4 < 16; ++d4) {
            float4 hv = *(const float4*)&hs[w][d4 * 4];
            p0 += hv.x*wl0[d4*4] + hv.y*wl0[d4*4+1] + hv.z*wl0[d4*4+2] + hv.w*wl0[d4*4+3];
            p1 += hv.x*wl1[d4*4] + hv.y*wl1[d4*4+1] + hv.z*wl1[d4*4+2] + hv.w*wl1[d4*4+3];
        }
        PXl[w][t & 3][l] = p0; PXl[w][t & 3][64 + l] = p1;

        if (t == tc) {
            fire = true;
        } else if (t > tc) {
            float hh = 0.f, cc = 0.f;
            #pragma unroll
            for (int k = 0; k < 4; ++k) {
                int s2 = (t - 3 + k) & 3;
                float q0 = PXl[w][s2][l], q1 = PXl[w][s2][64 + l];
                if (k) {
                    #pragma unroll
                    for (int d4 = 0; d4 < 8; ++d4) {
                        float4 hv = *(const float4*)&hs2f[w][d4 * 4];
                        q0 += hv.x*lh0[d4*4] + hv.y*lh0[d4*4+1] + hv.z*lh0[d4*4+2] + hv.w*lh0[d4*4+3];
                        q1 += hv.x*lh1[d4*4] + hv.y*lh1[d4*4+1] + hv.z*lh1[d4*4+2] + hv.w*lh1[d4*4+3];
                    }
                }
                float f_ = __shfl(q0, l + 32), o_ = __shfl(q1, l + 32);
                float ig = sigf(q0), ff = sigf(f_), gg = tanhf(q1), oo = sigf(o_);
                float ncc = ff * cc + ig * gg;
                float nhh = oo * tanhf(ncc);
                if (l < 32) { cc = ncc; hh = nhh; hs2f[w][l] = nhh; }
            }
            float pp = (l < 32) ? hh * twr : 0.f;
            #pragma unroll
            for (int o = 32; o; o >>= 1) pp += __shfl_xor(pp, o);
            if (l == 0) {
                float prob = sigf(pp + tb0);
                unsigned long long q = (unsigned long long)llrint((double)prob * 134217728.0);
                if (q > 0x7FFFFFFull) q = 0x7FFFFFFull;
                probq[w] = (unsigned int)q;
            }
            __syncthreads();
            if (w == 0 && l == 0) {
                unsigned int s = probq[0] + probq[1] + probq[2] + probq[3];
                __hip_atomic_store(&S2[(size_t)t * 256 + b], (1u << 30) | s,
                                   __ATOMIC_RELAXED, __HIP_MEMORY_SCOPE_AGENT);
            }
            if (w == 0) {
                unsigned long long tot = 0; int spin = 0; bool ok = true;
                if (!brk) {
                    for (;;) {
                        bool all4 = true; tot = 0;
                        #pragma unroll
                        for (int k2 = 0; k2 < 4; ++k2) {
                            unsigned int v = __hip_atomic_load(&S2[(size_t)t * 256 + k2 * 64 + l],
                                                               __ATOMIC_RELAXED, __HIP_MEMORY_SCOPE_AGENT);
                            all4 &= ((v >> 30) == 1u);
                            tot += (v & 0x3FFFFFFFu);
                        }
                        if (__all(all4)) break;
                        if (++spin > SPIN_BOUND) { ok = false; brk = true; break; }
                        __builtin_amdgcn_s_sleep(1);
                    }
                } else ok = false;
                #pragma unroll
                for (int o = 32; o; o >>= 1) tot += __shfl_xor(tot, o);
                int dec = (ok && tot > THRESH27) ? 1 : 0;
                cnt += dec;
                if (l == 0) flagLds = dec;
            }
            __syncthreads();
            fire = (flagLds != 0);
        }
    }

    // overwrite logits from exact replayed h
    float sL = hb[l];
    #pragma unroll
    for (int d4 = 0; d4 < 16; ++d4) {
        float4 w4 = *(const float4*)(hw + (size_t)l * 64 + d4 * 4);
        float4 hv = *(const float4*)&hs[w][d4 * 4];
        sL += hv.x * w4.x + hv.y * w4.y + hv.z * w4.z + hv.w * w4.w;
    }
    out[r * 64 + l] = sL;
    if (b == 0 && w == 0 && l == 0)
        out[65536] = brk ? -1234.f : (float)cnt / 256.f;
}

extern "C" void kernel_launch(void* const* d_in, const int* in_sizes, int n_in,
                              void* d_out, int out_size, void* d_ws, size_t ws_size,
                              hipStream_t stream)
{
    const int*   seq    = (const int*)d_in[0];
    const float* memory = (const float*)d_in[1];
    const float* embed  = (const float*)d_in[2];
    const float* gwih   = (const float*)d_in[3];
    const float* gwhh   = (const float*)d_in[4];
    const float* gbih   = (const float*)d_in[5];
    const float* gbhh   = (const float*)d_in[6];
    const float* qw     = (const float*)d_in[7];
    const float* qb     = (const float*)d_in[8];
    const float* kw     = (const float*)d_in[9];
    // d_in[10] = k_b : cancels in softmax, unused
    const float* vw     = (const float*)d_in[11];
    const float* vb     = (const float*)d_in[12];
    const float* lwih   = (const float*)d_in[13];
    const float* lwhh   = (const float*)d_in[14];
    const float* lbih   = (const float*)d_in[15];
    const float* lbhh   = (const float*)d_in[16];
    const float* tw     = (const float*)d_in[17];
    const float* tb     = (const float*)d_in[18];
    const float* hw     = (const float*)d_in[19];
    const float* hb     = (const float*)d_in[20];
    float* ws = (float*)d_ws;
    float* out = (float*)d_out;

    prep_k<<<80, 64, 0, stream>>>(embed, gwih, gbih, ws);
    gru_k<<<256, 256, 0, stream>>>(seq, gwhh, gbhh, hw, hb, ws, out);
    trig_k<<<4096, 256, 0, stream>>>(lwih, lwhh, lbih, lbhh, tw, tb, ws);
    red_k<<<64, 256, 0, stream>>>(ws);
    fin_k<<<256, 256, 0, stream>>>(seq, memory, gwih, gwhh, gbhh, qw, qb, kw,
                                   vw, vb, lwih, lwhh, lbih, lbhh, tw, tb,
                                   hw, hb, ws, out);
}

// Round 12
// 983.257 us; speedup vs baseline: 2.2876x; 1.1153x over previous
//
#include <hip/hip_runtime.h>
#include <hip/hip_fp16.h>
#include <math.h>

// ws float offsets
#define OFF_TOKPROJ 0         // 12288 floats
#define OFF_ACC     12288     // 256 u64 = 512 floats (exact q30 prob sums)
#define OFF_SLOT2   12800     // 256*256 u32 (rare path, tagged q27 sums)
#define OFF_HH      78336     // 1024*256*64 fp16 = 8388608 floats
// total = 8,466,944 floats = 33.87 MB

#define THRESH30 (512ULL << 30)
#define THRESH27 (512ULL << 27)
#define SPIN_BOUND (1 << 18)

// fast transcendentals: v_exp_f32 + fast rcp (~2 ulp), 4-5x fewer instrs than libm
__device__ __forceinline__ float sigf(float x) {
    return __fdividef(1.f, 1.f + __expf(-x));
}
__device__ __forceinline__ float tanhf_fast(float x) {
    float e2 = __expf(-2.f * fabsf(x));
    float r = __fdividef(1.f - e2, 1.f + e2);           // >= 0
    return __uint_as_float(__float_as_uint(r) | (__float_as_uint(x) & 0x80000000u));
}

// ---------------- prep: tokproj table + zero ACC/SLOT2 ----------------
__global__ __launch_bounds__(64) void prep_k(
    const float* __restrict__ embed, const float* __restrict__ gwih,
    const float* __restrict__ gbih, float* __restrict__ ws)
{
    int blk = blockIdx.x, l = threadIdx.x;
    if (blk < 64) {
        float* tokproj = ws + OFF_TOKPROJ;
        int v = blk;
        for (int j = l; j < 192; j += 64) {
            float s = gbih[j];
            for (int d = 0; d < 64; ++d) s += embed[v * 64 + d] * gwih[j * 128 + d];
            tokproj[v * 192 + j] = s;
        }
    } else {
        float* z = ws + OFF_ACC;
        int base = (blk - 64) * 4096;
        int end = 512 + 65536;
        for (int i = base + l; i < base + 4096; i += 64)
            if (i < end) z[i] = 0.f;
    }
}

// ---------------- k1: GRU-only recurrence + fp16 history + logits ----------
__global__ __launch_bounds__(256, 1) void gru_k(
    const int* __restrict__ seq, const float* __restrict__ gwhh,
    const float* __restrict__ gbhh, const float* __restrict__ hw,
    const float* __restrict__ hb, float* __restrict__ ws,
    float* __restrict__ out)
{
    int tid = threadIdx.x, w = tid >> 6, l = tid & 63, b = blockIdx.x;
    int r = b * 4 + w;
    const float* tokproj = ws + OFF_TOKPROJ;
    __half* Hh = (__half*)(ws + OFF_HH);

    __shared__ float hs[4][64];
    __shared__ int toks[4][256];
    for (int k = 0; k < 4; ++k) toks[w][k * 64 + l] = seq[r * 256 + k * 64 + l];

    float wh0[64], wh1[64], wh2[64];
    #pragma unroll
    for (int d4 = 0; d4 < 16; ++d4) {
        float4 a0 = *(const float4*)(gwhh + (size_t)l * 64 + d4 * 4);
        float4 a1 = *(const float4*)(gwhh + (size_t)(64 + l) * 64 + d4 * 4);
        float4 a2 = *(const float4*)(gwhh + (size_t)(128 + l) * 64 + d4 * 4);
        wh0[d4*4] = a0.x; wh0[d4*4+1] = a0.y; wh0[d4*4+2] = a0.z; wh0[d4*4+3] = a0.w;
        wh1[d4*4] = a1.x; wh1[d4*4+1] = a1.y; wh1[d4*4+2] = a1.z; wh1[d4*4+3] = a1.w;
        wh2[d4*4] = a2.x; wh2[d4*4+1] = a2.y; wh2[d4*4+2] = a2.z; wh2[d4*4+3] = a2.w;
    }
    float g0b = gbhh[l], g1b = gbhh[64 + l], g2b = gbhh[128 + l];

    float h = 0.f;
    hs[w][l] = 0.f;
    int tok0 = toks[w][0];
    float gi0 = tokproj[tok0 * 192 + l], gi1 = tokproj[tok0 * 192 + 64 + l],
          gi2 = tokproj[tok0 * 192 + 128 + l];

    for (int t = 0; t < 256; ++t) {
        float ni0 = 0.f, ni1 = 0.f, ni2 = 0.f;
        if (t < 255) {
            int tk = toks[w][t + 1];
            ni0 = tokproj[tk * 192 + l];
            ni1 = tokproj[tk * 192 + 64 + l];
            ni2 = tokproj[tk * 192 + 128 + l];
        }
        float gh0 = g0b, gh1 = g1b, gh2 = g2b;
        #pragma unroll
        for (int d4 = 0; d4 < 16; ++d4) {
            float4 hv = *(const float4*)&hs[w][d4 * 4];
            gh0 += hv.x*wh0[d4*4] + hv.y*wh0[d4*4+1] + hv.z*wh0[d4*4+2] + hv.w*wh0[d4*4+3];
            gh1 += hv.x*wh1[d4*4] + hv.y*wh1[d4*4+1] + hv.z*wh1[d4*4+2] + hv.w*wh1[d4*4+3];
            gh2 += hv.x*wh2[d4*4] + hv.y*wh2[d4*4+1] + hv.z*wh2[d4*4+2] + hv.w*wh2[d4*4+3];
        }
        float r_ = sigf(gi0 + gh0), z_ = sigf(gi1 + gh1);
        float n_ = tanhf_fast(gi2 + r_ * gh2);
        h = (1.f - z_) * n_ + z_ * h;
        hs[w][l] = h;
        Hh[((size_t)r * 256 + t) * 64 + l] = __float2half(h);
        gi0 = ni0; gi1 = ni1; gi2 = ni2;
    }

    // logits from exact h_255
    float sL = hb[l];
    #pragma unroll
    for (int d4 = 0; d4 < 16; ++d4) {
        float4 w4 = *(const float4*)(hw + (size_t)l * 64 + d4 * 4);
        float4 hv = *(const float4*)&hs[w][d4 * 4];
        sL += hv.x * w4.x + hv.y * w4.y + hv.z * w4.z + hv.w * w4.w;
    }
    out[r * 64 + l] = sL;
}

// ---------------- k2: all triggers in parallel; exact atomic prob sums -----
__global__ __launch_bounds__(256, 1) void trig_k(
    const float* __restrict__ lwih, const float* __restrict__ lwhh,
    const float* __restrict__ lbih, const float* __restrict__ lbhh,
    const float* __restrict__ tw, const float* __restrict__ tb,
    float* __restrict__ ws)
{
    int tid = threadIdx.x, w = tid >> 6, l = tid & 63, b = blockIdx.x;
    int rg = b >> 4, c = b & 15;
    int r = rg * 4 + w;
    int t0 = 3 + 16 * c;
    int ntrig = (c == 15) ? 13 : 16;
    int wlen = ntrig + 3;

    const __half* Hh = (const __half*)(ws + OFF_HH);
    unsigned long long* acc = (unsigned long long*)(ws + OFF_ACC);

    __shared__ float hwin[4][19][64];
    __shared__ float pwin[4][19][128];
    __shared__ float hs2[4][32];
    __shared__ unsigned int probq[4][16];

    float wl0[64], wl1[64], lh0[32], lh1[32];
    #pragma unroll
    for (int d4 = 0; d4 < 16; ++d4) {
        float4 b0 = *(const float4*)(lwih + (size_t)l * 64 + d4 * 4);
        float4 b1 = *(const float4*)(lwih + (size_t)(64 + l) * 64 + d4 * 4);
        wl0[d4*4] = b0.x; wl0[d4*4+1] = b0.y; wl0[d4*4+2] = b0.z; wl0[d4*4+3] = b0.w;
        wl1[d4*4] = b1.x; wl1[d4*4+1] = b1.y; wl1[d4*4+2] = b1.z; wl1[d4*4+3] = b1.w;
    }
    #pragma unroll
    for (int d4 = 0; d4 < 8; ++d4) {
        float4 c0 = *(const float4*)(lwhh + (size_t)l * 32 + d4 * 4);
        float4 c1 = *(const float4*)(lwhh + (size_t)(64 + l) * 32 + d4 * 4);
        lh0[d4*4] = c0.x; lh0[d4*4+1] = c0.y; lh0[d4*4+2] = c0.z; lh0[d4*4+3] = c0.w;
        lh1[d4*4] = c1.x; lh1[d4*4+1] = c1.y; lh1[d4*4+2] = c1.z; lh1[d4*4+3] = c1.w;
    }
    float lb0 = lbih[l] + lbhh[l], lb1 = lbih[64 + l] + lbhh[64 + l];
    float twr = (l < 32) ? tw[l] : 0.f;
    float tb0 = tb[0];

    // stage fp16 h window -> fp32 LDS
    for (int i = 0; i < wlen; ++i)
        hwin[w][i][l] = __half2float(Hh[((size_t)r * 256 + (t0 - 3 + i)) * 64 + l]);

    // projections (shared across triggers)
    for (int i = 0; i < wlen; ++i) {
        float p0 = lb0, p1 = lb1;
        #pragma unroll
        for (int d4 = 0; d4 < 16; ++d4) {
            float4 hv = *(const float4*)&hwin[w][i][d4 * 4];
            p0 += hv.x*wl0[d4*4] + hv.y*wl0[d4*4+1] + hv.z*wl0[d4*4+2] + hv.w*wl0[d4*4+3];
            p1 += hv.x*wl1[d4*4] + hv.y*wl1[d4*4+1] + hv.z*wl1[d4*4+2] + hv.w*wl1[d4*4+3];
        }
        pwin[w][i][l] = p0; pwin[w][i][64 + l] = p1;
    }

    // triggers
    for (int j = 0; j < ntrig; ++j) {
        float hh = 0.f, cc = 0.f;
        #pragma unroll
        for (int k = 0; k < 4; ++k) {
            float q0 = pwin[w][j + k][l], q1 = pwin[w][j + k][64 + l];
            if (k) {
                #pragma unroll
                for (int d4 = 0; d4 < 8; ++d4) {
                    float4 hv = *(const float4*)&hs2[w][d4 * 4];
                    q0 += hv.x*lh0[d4*4] + hv.y*lh0[d4*4+1] + hv.z*lh0[d4*4+2] + hv.w*lh0[d4*4+3];
                    q1 += hv.x*lh1[d4*4] + hv.y*lh1[d4*4+1] + hv.z*lh1[d4*4+2] + hv.w*lh1[d4*4+3];
                }
            }
            float f_ = __shfl(q0, l + 32), o_ = __shfl(q1, l + 32);
            float ig = sigf(q0), ff = sigf(f_), gg = tanhf_fast(q1), oo = sigf(o_);
            float ncc = ff * cc + ig * gg;
            float nhh = oo * tanhf_fast(ncc);
            if (l < 32) { cc = ncc; hh = nhh; hs2[w][l] = nhh; }
        }
        float pp = (l < 32) ? hh * twr : 0.f;
        #pragma unroll
        for (int o = 32; o; o >>= 1) pp += __shfl_xor(pp, o);
        if (l == 0) {
            float prob = sigf(pp + tb0);
            unsigned long long q = (unsigned long long)llrint((double)prob * 1073741824.0);
            if (q > 0x3FFFFFFFull) q = 0x3FFFFFFFull;
            probq[w][j] = (unsigned int)q;
        }
    }
    __syncthreads();
    if (w == 0 && l < ntrig) {
        unsigned int s = probq[0][l] + probq[1][l] + probq[2][l] + probq[3][l];
        atomicAdd(&acc[t0 + l], (unsigned long long)s);   // exact integer, deterministic
    }
}

// ---------------- k3: inline verdict; no-op on no-fire; replay on fire -----
__global__ __launch_bounds__(256, 1) void fin_k(
    const int* __restrict__ seq, const float* __restrict__ memory,
    const float* __restrict__ gwih, const float* __restrict__ gwhh,
    const float* __restrict__ gbhh, const float* __restrict__ qw,
    const float* __restrict__ qb, const float* __restrict__ kw,
    const float* __restrict__ vw, const float* __restrict__ vb,
    const float* __restrict__ lwih, const float* __restrict__ lwhh,
    const float* __restrict__ lbih, const float* __restrict__ lbhh,
    const float* __restrict__ tw, const float* __restrict__ tb,
    const float* __restrict__ hw, const float* __restrict__ hb,
    float* __restrict__ ws, float* __restrict__ out)
{
    int tid = threadIdx.x, w = tid >> 6, l = tid & 63, b = blockIdx.x;
    const unsigned long long* acc = (const unsigned long long*)(ws + OFF_ACC);

    // ---- inline verdict from exact sums (trig_k complete: stream order) ----
    __shared__ int redmin[4];
    {
        int mymin = 1 << 30;
        if (tid >= 3 && acc[tid] > THRESH30) mymin = tid;
        #pragma unroll
        for (int o = 32; o; o >>= 1) mymin = min(mymin, __shfl_xor(mymin, o));
        if (l == 0) redmin[w] = mymin;
    }
    __syncthreads();
    int tc = min(min(redmin[0], redmin[1]), min(redmin[2], redmin[3]));
    if (tc > 255) {
        if (b == 0 && tid == 0) out[65536] = 0.f;
        return;                         // common path
    }

    int r = b * 4 + w;
    const float* tokproj = ws + OFF_TOKPROJ;
    unsigned int* S2 = (unsigned int*)(ws + OFF_SLOT2);

    __shared__ float hs[4][64], qs[4][64], us[4][64], rs[4][64];
    __shared__ float hs2f[4][32];
    __shared__ float PXl[4][4][128];
    __shared__ unsigned int probq[4];
    __shared__ int flagLds;
    __shared__ int toks[4][256];

    for (int k = 0; k < 4; ++k) toks[w][k * 64 + l] = seq[r * 256 + k * 64 + l];
    if (tid == 0) flagLds = 0;

    float wh0[64], wh1[64], wh2[64], wl0[64], wl1[64], lh0[32], lh1[32];
    #pragma unroll
    for (int d4 = 0; d4 < 16; ++d4) {
        float4 a0 = *(const float4*)(gwhh + (size_t)l * 64 + d4 * 4);
        float4 a1 = *(const float4*)(gwhh + (size_t)(64 + l) * 64 + d4 * 4);
        float4 a2 = *(const float4*)(gwhh + (size_t)(128 + l) * 64 + d4 * 4);
        float4 b0 = *(const float4*)(lwih + (size_t)l * 64 + d4 * 4);
        float4 b1 = *(const float4*)(lwih + (size_t)(64 + l) * 64 + d4 * 4);
        wh0[d4*4] = a0.x; wh0[d4*4+1] = a0.y; wh0[d4*4+2] = a0.z; wh0[d4*4+3] = a0.w;
        wh1[d4*4] = a1.x; wh1[d4*4+1] = a1.y; wh1[d4*4+2] = a1.z; wh1[d4*4+3] = a1.w;
        wh2[d4*4] = a2.x; wh2[d4*4+1] = a2.y; wh2[d4*4+2] = a2.z; wh2[d4*4+3] = a2.w;
        wl0[d4*4] = b0.x; wl0[d4*4+1] = b0.y; wl0[d4*4+2] = b0.z; wl0[d4*4+3] = b0.w;
        wl1[d4*4] = b1.x; wl1[d4*4+1] = b1.y; wl1[d4*4+2] = b1.z; wl1[d4*4+3] = b1.w;
    }
    #pragma unroll
    for (int d4 = 0; d4 < 8; ++d4) {
        float4 c0 = *(const float4*)(lwhh + (size_t)l * 32 + d4 * 4);
        float4 c1 = *(const float4*)(lwhh + (size_t)(64 + l) * 32 + d4 * 4);
        lh0[d4*4] = c0.x; lh0[d4*4+1] = c0.y; lh0[d4*4+2] = c0.z; lh0[d4*4+3] = c0.w;
        lh1[d4*4] = c1.x; lh1[d4*4+1] = c1.y; lh1[d4*4+2] = c1.z; lh1[d4*4+3] = c1.w;
    }
    float g0b = gbhh[l], g1b = gbhh[64 + l], g2b = gbhh[128 + l];
    float lb0 = lbih[l] + lbhh[l], lb1 = lbih[64 + l] + lbhh[64 + l];
    float twr = (l < 32) ? tw[l] : 0.f;
    float tb0 = tb[0];
    const float* mrow = memory + (size_t)r * 16384;

    float h = 0.f;
    hs[w][l] = 0.f;
    bool fire = false, brk = false;
    int cnt = 1;
    __syncthreads();

    for (int t = 0; t < 256; ++t) {
        int tok = toks[w][t];
        float gi0 = tokproj[tok * 192 + l], gi1 = tokproj[tok * 192 + 64 + l],
              gi2 = tokproj[tok * 192 + 128 + l];
        float gh0 = g0b, gh1 = g1b, gh2 = g2b;
        #pragma unroll
        for (int d4 = 0; d4 < 16; ++d4) {
            float4 hv = *(const float4*)&hs[w][d4 * 4];
            gh0 += hv.x*wh0[d4*4] + hv.y*wh0[d4*4+1] + hv.z*wh0[d4*4+2] + hv.w*wh0[d4*4+3];
            gh1 += hv.x*wh1[d4*4] + hv.y*wh1[d4*4+1] + hv.z*wh1[d4*4+2] + hv.w*wh1[d4*4+3];
            gh2 += hv.x*wh2[d4*4] + hv.y*wh2[d4*4+1] + hv.z*wh2[d4*4+2] + hv.w*wh2[d4*4+3];
        }
        if (fire) {
            // ---- unfused exact attention on h_{t-1} ----
            float q = qb[l];
            #pragma unroll
            for (int d4 = 0; d4 < 16; ++d4) {
                float4 q4 = *(const float4*)(qw + (size_t)l * 64 + d4 * 4);
                float4 hv = *(const float4*)&hs[w][d4 * 4];
                q += hv.x * q4.x + hv.y * q4.y + hv.z * q4.z + hv.w * q4.w;
            }
            qs[w][l] = q;
            float qk = 0.f;
            for (int e = 0; e < 64; ++e) qk += qs[w][e] * kw[(size_t)e * 64 + l];
            qk *= 0.125f;
            us[w][l] = qk;
            float sc[4];
            for (int k = 0; k < 4; ++k) {
                const float* mp = mrow + (size_t)(k * 64 + l) * 64;
                float s = 0.f;
                #pragma unroll
                for (int d4 = 0; d4 < 16; ++d4) {
                    float4 m4 = *(const float4*)(mp + d4 * 4);
                    float4 kv = *(const float4*)&us[w][d4 * 4];
                    s += m4.x * kv.x + m4.y * kv.y + m4.z * kv.z + m4.w * kv.w;
                }
                sc[k] = s;
            }
            float mx = fmaxf(fmaxf(sc[0], sc[1]), fmaxf(sc[2], sc[3]));
            for (int o = 32; o; o >>= 1) mx = fmaxf(mx, __shfl_xor(mx, o));
            float den = 0.f;
            #pragma unroll
            for (int k = 0; k < 4; ++k) { sc[k] = expf(sc[k] - mx); den += sc[k]; }
            for (int o = 32; o; o >>= 1) den += __shfl_xor(den, o);
            float u = 0.f;
            for (int m = 0; m < 256; ++m) {
                float wm = __shfl(sc[m >> 6], m & 63);
                u += wm * mrow[(size_t)m * 64 + l];
            }
            u /= den;
            us[w][l] = u;
            float ret = vb[l];
            #pragma unroll
            for (int d4 = 0; d4 < 16; ++d4) {
                float4 v4 = *(const float4*)(vw + (size_t)l * 64 + d4 * 4);
                float4 uv = *(const float4*)&us[w][d4 * 4];
                ret += uv.x * v4.x + uv.y * v4.y + uv.z * v4.z + uv.w * v4.w;
            }
            rs[w][l] = ret;
            for (int e = 0; e < 64; ++e) {
                float re = rs[w][e];
                gi0 += re * gwih[(size_t)l * 128 + 64 + e];
                gi1 += re * gwih[(size_t)(64 + l) * 128 + 64 + e];
                gi2 += re * gwih[(size_t)(128 + l) * 128 + 64 + e];
            }
        }
        fire = false;
        float r_ = sigf(gi0 + gh0), z_ = sigf(gi1 + gh1);
        float n_ = tanhf_fast(gi2 + r_ * gh2);
        h = (1.f - z_) * n_ + z_ * h;
        hs[w][l] = h;

        float p0 = lb0, p1 = lb1;
        #pragma unroll
        for (int d4 = 0; d4 < 16; ++d4) {
            float4 hv = *(const float4*)&hs[w][d4 * 4];
            p0 += hv.x*wl0[d4*4] + hv.y*wl0[d4*4+1] + hv.z*wl0[d4*4+2] + hv.w*wl0[d4*4+3];
            p1 += hv.x*wl1[d4*4] + hv.y*wl1[d4*4+1] + hv.z*wl1[d4*4+2] + hv.w*wl1[d4*4+3];
        }
        PXl[w][t & 3][l] = p0; PXl[w][t & 3][64 + l] = p1;

        if (t == tc) {
            fire = true;
        } else if (t > tc) {
            float hh = 0.f, cc = 0.f;
            #pragma unroll
            for (int k = 0; k < 4; ++k) {
                int s2 = (t - 3 + k) & 3;
                float q0 = PXl[w][s2][l], q1 = PXl[w][s2][64 + l];
                if (k) {
                    #pragma unroll
                    for (int d4 = 0; d4 < 8; ++d4) {
                        float4 hv = *(const float4*)&hs2f[w][d4 * 4];
                        q0 += hv.x*lh0[d4*4] + hv.y*lh0[d4*4+1] + hv.z*lh0[d4*4+2] + hv.w*lh0[d4*4+3];
                        q1 += hv.x*lh1[d4*4] + hv.y*lh1[d4*4+1] + hv.z*lh1[d4*4+2] + hv.w*lh1[d4*4+3];
                    }
                }
                float f_ = __shfl(q0, l + 32), o_ = __shfl(q1, l + 32);
                float ig = sigf(q0), ff = sigf(f_), gg = tanhf_fast(q1), oo = sigf(o_);
                float ncc = ff * cc + ig * gg;
                float nhh = oo * tanhf_fast(ncc);
                if (l < 32) { cc = ncc; hh = nhh; hs2f[w][l] = nhh; }
            }
            float pp = (l < 32) ? hh * twr : 0.f;
            #pragma unroll
            for (int o = 32; o; o >>= 1) pp += __shfl_xor(pp, o);
            if (l == 0) {
                float prob = sigf(pp + tb0);
                unsigned long long q = (unsigned long long)llrint((double)prob * 134217728.0);
                if (q > 0x7FFFFFFull) q = 0x7FFFFFFull;
                probq[w] = (unsigned int)q;
            }
            __syncthreads();
            if (w == 0 && l == 0) {
                unsigned int s = probq[0] + probq[1] + probq[2] + probq[3];
                __hip_atomic_store(&S2[(size_t)t * 256 + b], (1u << 30) | s,
                                   __ATOMIC_RELAXED, __HIP_MEMORY_SCOPE_AGENT);
            }
            if (w == 0) {
                unsigned long long tot = 0; int spin = 0; bool ok = true;
                if (!brk) {
                    for (;;) {
                        bool all4 = true; tot = 0;
                        #pragma unroll
                        for (int k2 = 0; k2 < 4; ++k2) {
                            unsigned int v = __hip_atomic_load(&S2[(size_t)t * 256 + k2 * 64 + l],
                                                               __ATOMIC_RELAXED, __HIP_MEMORY_SCOPE_AGENT);
                            all4 &= ((v >> 30) == 1u);
                            tot += (v & 0x3FFFFFFFu);
                        }
                        if (__all(all4)) break;
                        if (++spin > SPIN_BOUND) { ok = false; brk = true; break; }
                        __builtin_amdgcn_s_sleep(1);
                    }
                } else ok = false;
                #pragma unroll
                for (int o = 32; o; o >>= 1) tot += __shfl_xor(tot, o);
                int dec = (ok && tot > THRESH27) ? 1 : 0;
                cnt += dec;
                if (l == 0) flagLds = dec;
            }
            __syncthreads();
            fire = (flagLds != 0);
        }
    }

    // overwrite logits from exact replayed h
    float sL = hb[l];
    #pragma unroll
    for (int d4 = 0; d4 < 16; ++d4) {
        float4 w4 = *(const float4*)(hw + (size_t)l * 64 + d4 * 4);
        float4 hv = *(const float4*)&hs[w][d4 * 4];
        sL += hv.x * w4.x + hv.y * w4.y + hv.z * w4.z + hv.w * w4.w;
    }
    out[r * 64 + l] = sL;
    if (b == 0 && w == 0 && l == 0)
        out[65536] = brk ? -1234.f : (float)cnt / 256.f;
}

extern "C" void kernel_launch(void* const* d_in, const int* in_sizes, int n_in,
                              void* d_out, int out_size, void* d_ws, size_t ws_size,
                              hipStream_t stream)
{
    const int*   seq    = (const int*)d_in[0];
    const float* memory = (const float*)d_in[1];
    const float* embed  = (const float*)d_in[2];
    const float* gwih   = (const float*)d_in[3];
    const float* gwhh   = (const float*)d_in[4];
    const float* gbih   = (const float*)d_in[5];
    const float* gbhh   = (const float*)d_in[6];
    const float* qw     = (const float*)d_in[7];
    const float* qb     = (const float*)d_in[8];
    const float* kw     = (const float*)d_in[9];
    // d_in[10] = k_b : cancels in softmax, unused
    const float* vw     = (const float*)d_in[11];
    const float* vb     = (const float*)d_in[12];
    const float* lwih   = (const float*)d_in[13];
    const float* lwhh   = (const float*)d_in[14];
    const float* lbih   = (const float*)d_in[15];
    const float* lbhh   = (const float*)d_in[16];
    const float* tw     = (const float*)d_in[17];
    const float* tb     = (const float*)d_in[18];
    const float* hw     = (const float*)d_in[19];
    const float* hb     = (const float*)d_in[20];
    float* ws = (float*)d_ws;
    float* out = (float*)d_out;

    prep_k<<<81, 64, 0, stream>>>(embed, gwih, gbih, ws);
    gru_k<<<256, 256, 0, stream>>>(seq, gwhh, gbhh, hw, hb, ws, out);
    trig_k<<<4096, 256, 0, stream>>>(lwih, lwhh, lbih, lbhh, tw, tb, ws);
    fin_k<<<256, 256, 0, stream>>>(seq, memory, gwih, gwhh, gbhh, qw, qb, kw,
                                   vw, vb, lwih, lwhh, lbih, lbhh, tw, tb,
                                   hw, hb, ws, out);
}

// Round 13
// 592.743 us; speedup vs baseline: 3.7948x; 1.6588x over previous
//
#include <hip/hip_runtime.h>
#include <hip/hip_fp16.h>
#include <math.h>

// ws float offsets
#define OFF_TOKPROJ 0         // 12288 floats
#define OFF_ACC     12288     // 256 u64 = 512 floats (exact q30 prob sums)
#define OFF_SLOT2   12800     // 256*256 u32 (rare path, tagged q27 sums)
#define OFF_HH      78336     // 1024*256*64 fp16 = 8388608 floats
// total = 8,466,944 floats = 33.87 MB

#define THRESH30 (512ULL << 30)
#define THRESH27 (512ULL << 27)
#define SPIN_BOUND (1 << 18)

// fast transcendentals: v_exp_f32 + fast rcp (~2 ulp)
__device__ __forceinline__ float sigf(float x) {
    return __fdividef(1.f, 1.f + __expf(-x));
}
__device__ __forceinline__ float tanhf_fast(float x) {
    float e2 = __expf(-2.f * fabsf(x));
    float r = __fdividef(1.f - e2, 1.f + e2);           // >= 0
    return __uint_as_float(__float_as_uint(r) | (__float_as_uint(x) & 0x80000000u));
}

__device__ __forceinline__ unsigned int pack2(float x, float y) {
    union { unsigned int u; _Float16 h[2]; } v;
    v.h[0] = (_Float16)x; v.h[1] = (_Float16)y;
    return v.u;
}
__device__ __forceinline__ float dot2acc(unsigned int a, unsigned int b, float acc) {
#if __has_builtin(__builtin_amdgcn_fdot2)
    typedef _Float16 hf2 __attribute__((ext_vector_type(2)));
    union { unsigned int u; hf2 h; } ua, ub;
    ua.u = a; ub.u = b;
    return __builtin_amdgcn_fdot2(ua.h, ub.h, acc, false);
#else
    union { unsigned int u; _Float16 h[2]; } ua, ub;
    ua.u = a; ub.u = b;
    return acc + (float)ua.h[0] * (float)ub.h[0] + (float)ua.h[1] * (float)ub.h[1];
#endif
}

// ---------------- prep: tokproj table + zero ACC/SLOT2 ----------------
__global__ __launch_bounds__(64) void prep_k(
    const float* __restrict__ embed, const float* __restrict__ gwih,
    const float* __restrict__ gbih, float* __restrict__ ws)
{
    int blk = blockIdx.x, l = threadIdx.x;
    if (blk < 64) {
        float* tokproj = ws + OFF_TOKPROJ;
        int v = blk;
        for (int j = l; j < 192; j += 64) {
            float s = gbih[j];
            for (int d = 0; d < 64; ++d) s += embed[v * 64 + d] * gwih[j * 128 + d];
            tokproj[v * 192 + j] = s;
        }
    } else {
        float* z = ws + OFF_ACC;
        int base = (blk - 64) * 4096;
        int end = 512 + 65536;
        for (int i = base + l; i < base + 4096; i += 64)
            if (i < end) z[i] = 0.f;
    }
}

// ---------------- k1: GRU-only recurrence + fp16 history + logits ----------
__global__ __launch_bounds__(256, 1) void gru_k(
    const int* __restrict__ seq, const float* __restrict__ gwhh,
    const float* __restrict__ gbhh, const float* __restrict__ hw,
    const float* __restrict__ hb, float* __restrict__ ws,
    float* __restrict__ out)
{
    int tid = threadIdx.x, w = tid >> 6, l = tid & 63, b = blockIdx.x;
    int r = b * 4 + w;
    const float* tokproj = ws + OFF_TOKPROJ;
    __half* Hh = (__half*)(ws + OFF_HH);

    __shared__ float hs[4][64];
    __shared__ int toks[4][256];
    for (int k = 0; k < 4; ++k) toks[w][k * 64 + l] = seq[r * 256 + k * 64 + l];

    float wh0[64], wh1[64], wh2[64];
    #pragma unroll
    for (int d4 = 0; d4 < 16; ++d4) {
        float4 a0 = *(const float4*)(gwhh + (size_t)l * 64 + d4 * 4);
        float4 a1 = *(const float4*)(gwhh + (size_t)(64 + l) * 64 + d4 * 4);
        float4 a2 = *(const float4*)(gwhh + (size_t)(128 + l) * 64 + d4 * 4);
        wh0[d4*4] = a0.x; wh0[d4*4+1] = a0.y; wh0[d4*4+2] = a0.z; wh0[d4*4+3] = a0.w;
        wh1[d4*4] = a1.x; wh1[d4*4+1] = a1.y; wh1[d4*4+2] = a1.z; wh1[d4*4+3] = a1.w;
        wh2[d4*4] = a2.x; wh2[d4*4+1] = a2.y; wh2[d4*4+2] = a2.z; wh2[d4*4+3] = a2.w;
    }
    float g0b = gbhh[l], g1b = gbhh[64 + l], g2b = gbhh[128 + l];

    float h = 0.f;
    hs[w][l] = 0.f;
    int tok0 = toks[w][0];
    float gi0 = tokproj[tok0 * 192 + l], gi1 = tokproj[tok0 * 192 + 64 + l],
          gi2 = tokproj[tok0 * 192 + 128 + l];

    for (int t = 0; t < 256; ++t) {
        float ni0 = 0.f, ni1 = 0.f, ni2 = 0.f;
        if (t < 255) {
            int tk = toks[w][t + 1];
            ni0 = tokproj[tk * 192 + l];
            ni1 = tokproj[tk * 192 + 64 + l];
            ni2 = tokproj[tk * 192 + 128 + l];
        }
        float gh0 = g0b, gh1 = g1b, gh2 = g2b;
        #pragma unroll
        for (int d4 = 0; d4 < 16; ++d4) {
            float4 hv = *(const float4*)&hs[w][d4 * 4];
            gh0 += hv.x*wh0[d4*4] + hv.y*wh0[d4*4+1] + hv.z*wh0[d4*4+2] + hv.w*wh0[d4*4+3];
            gh1 += hv.x*wh1[d4*4] + hv.y*wh1[d4*4+1] + hv.z*wh1[d4*4+2] + hv.w*wh1[d4*4+3];
            gh2 += hv.x*wh2[d4*4] + hv.y*wh2[d4*4+1] + hv.z*wh2[d4*4+2] + hv.w*wh2[d4*4+3];
        }
        float r_ = sigf(gi0 + gh0), z_ = sigf(gi1 + gh1);
        float n_ = tanhf_fast(gi2 + r_ * gh2);
        h = (1.f - z_) * n_ + z_ * h;
        hs[w][l] = h;
        Hh[((size_t)r * 256 + t) * 64 + l] = __float2half(h);
        gi0 = ni0; gi1 = ni1; gi2 = ni2;
    }

    // logits from exact h_255
    float sL = hb[l];
    #pragma unroll
    for (int d4 = 0; d4 < 16; ++d4) {
        float4 w4 = *(const float4*)(hw + (size_t)l * 64 + d4 * 4);
        float4 hv = *(const float4*)&hs[w][d4 * 4];
        sL += hv.x * w4.x + hv.y * w4.y + hv.z * w4.z + hv.w * w4.w;
    }
    out[r * 64 + l] = sL;
}

// ---------------- k2: all triggers; packed-fp16 dot2 + 2-trigger ILP -------
__global__ __launch_bounds__(256, 1) void trig_k(
    const float* __restrict__ lwih, const float* __restrict__ lwhh,
    const float* __restrict__ lbih, const float* __restrict__ lbhh,
    const float* __restrict__ tw, const float* __restrict__ tb,
    float* __restrict__ ws)
{
    int tid = threadIdx.x, w = tid >> 6, l = tid & 63, b = blockIdx.x;
    int rg = b >> 4, c = b & 15;
    int r = rg * 4 + w;
    int t0 = 3 + 16 * c;
    int ntrig = (c == 15) ? 13 : 16;
    int wlen = ntrig + 3;

    const unsigned int* HhU = (const unsigned int*)(ws + OFF_HH);
    unsigned long long* acc = (unsigned long long*)(ws + OFF_ACC);

    __shared__ unsigned int hwin2[4][608];     // 19 x 32 half2 per wave
    __shared__ float pwin[4][19][128];
    __shared__ unsigned int hs2p[4][2][16];    // packed LSTM hidden (A,B chains)
    __shared__ unsigned int probq[4][16];

    // ---- packed weights in registers: 96 VGPRs total ----
    unsigned int wl0h[32], wl1h[32], lh0h[16], lh1h[16];
    #pragma unroll
    for (int d2 = 0; d2 < 32; ++d2) {
        wl0h[d2] = pack2(lwih[(size_t)l * 64 + 2*d2], lwih[(size_t)l * 64 + 2*d2 + 1]);
        wl1h[d2] = pack2(lwih[(size_t)(64 + l) * 64 + 2*d2], lwih[(size_t)(64 + l) * 64 + 2*d2 + 1]);
    }
    #pragma unroll
    for (int d2 = 0; d2 < 16; ++d2) {
        lh0h[d2] = pack2(lwhh[(size_t)l * 32 + 2*d2], lwhh[(size_t)l * 32 + 2*d2 + 1]);
        lh1h[d2] = pack2(lwhh[(size_t)(64 + l) * 32 + 2*d2], lwhh[(size_t)(64 + l) * 32 + 2*d2 + 1]);
    }
    float lb0 = lbih[l] + lbhh[l], lb1 = lbih[64 + l] + lbhh[64 + l];
    float twr = (l < 32) ? tw[l] : 0.f;
    float tb0 = tb[0];

    // ---- stage packed h window (Hh already fp16; contiguous in t) ----
    for (int idx = l; idx < wlen * 32; idx += 64)
        hwin2[w][idx] = HhU[((size_t)r * 256 + (t0 - 3)) * 32 + idx];

    // ---- projections via fdot2 ----
    for (int i = 0; i < wlen; ++i) {
        float p0 = lb0, p1 = lb1;
        #pragma unroll
        for (int d8 = 0; d8 < 8; ++d8) {
            uint4 hv = *(const uint4*)&hwin2[w][i * 32 + d8 * 4];
            p0 = dot2acc(hv.x, wl0h[d8*4+0], p0); p1 = dot2acc(hv.x, wl1h[d8*4+0], p1);
            p0 = dot2acc(hv.y, wl0h[d8*4+1], p0); p1 = dot2acc(hv.y, wl1h[d8*4+1], p1);
            p0 = dot2acc(hv.z, wl0h[d8*4+2], p0); p1 = dot2acc(hv.z, wl1h[d8*4+2], p1);
            p0 = dot2acc(hv.w, wl0h[d8*4+3], p0); p1 = dot2acc(hv.w, wl1h[d8*4+3], p1);
        }
        pwin[w][i][l] = p0; pwin[w][i][64 + l] = p1;
    }

    // ---- triggers: 2 independent LSTM chains interleaved (j, j+8) ----
    for (int jp = 0; jp < 8 && jp < ntrig; ++jp) {
        int ja = jp, jb = jp + 8;
        bool hasB = (jb < ntrig);
        float hhA = 0.f, ccA = 0.f, hhB = 0.f, ccB = 0.f;
        #pragma unroll
        for (int k = 0; k < 4; ++k) {
            float q0A = pwin[w][ja + k][l], q1A = pwin[w][ja + k][64 + l];
            float q0B = 0.f, q1B = 0.f;
            if (hasB) { q0B = pwin[w][jb + k][l]; q1B = pwin[w][jb + k][64 + l]; }
            if (k) {
                #pragma unroll
                for (int d4 = 0; d4 < 4; ++d4) {
                    uint4 ha = *(const uint4*)&hs2p[w][0][d4 * 4];
                    q0A = dot2acc(ha.x, lh0h[d4*4+0], q0A); q1A = dot2acc(ha.x, lh1h[d4*4+0], q1A);
                    q0A = dot2acc(ha.y, lh0h[d4*4+1], q0A); q1A = dot2acc(ha.y, lh1h[d4*4+1], q1A);
                    q0A = dot2acc(ha.z, lh0h[d4*4+2], q0A); q1A = dot2acc(ha.z, lh1h[d4*4+2], q1A);
                    q0A = dot2acc(ha.w, lh0h[d4*4+3], q0A); q1A = dot2acc(ha.w, lh1h[d4*4+3], q1A);
                }
                if (hasB) {
                    #pragma unroll
                    for (int d4 = 0; d4 < 4; ++d4) {
                        uint4 hb2 = *(const uint4*)&hs2p[w][1][d4 * 4];
                        q0B = dot2acc(hb2.x, lh0h[d4*4+0], q0B); q1B = dot2acc(hb2.x, lh1h[d4*4+0], q1B);
                        q0B = dot2acc(hb2.y, lh0h[d4*4+1], q0B); q1B = dot2acc(hb2.y, lh1h[d4*4+1], q1B);
                        q0B = dot2acc(hb2.z, lh0h[d4*4+2], q0B); q1B = dot2acc(hb2.z, lh1h[d4*4+2], q1B);
                        q0B = dot2acc(hb2.w, lh0h[d4*4+3], q0B); q1B = dot2acc(hb2.w, lh1h[d4*4+3], q1B);
                    }
                }
            }
            // finish A
            float fA = __shfl(q0A, l + 32), oA = __shfl(q1A, l + 32);
            float igA = sigf(q0A), ffA = sigf(fA), ggA = tanhf_fast(q1A), ooA = sigf(oA);
            float nccA = ffA * ccA + igA * ggA;
            float nhA = ooA * tanhf_fast(nccA);
            if (l < 32) { ccA = nccA; hhA = nhA; }
            // finish B
            float nhB = 0.f;
            if (hasB) {
                float fB = __shfl(q0B, l + 32), oB = __shfl(q1B, l + 32);
                float igB = sigf(q0B), ffB = sigf(fB), ggB = tanhf_fast(q1B), ooB = sigf(oB);
                float nccB = ffB * ccB + igB * ggB;
                nhB = ooB * tanhf_fast(nccB);
                if (l < 32) { ccB = nccB; hhB = nhB; }
            }
            // repack hidden states for next step (needed only if k<3)
            if (k < 3) {
                float a0 = __shfl(nhA, 2 * l), a1 = __shfl(nhA, 2 * l + 1);
                if (l < 16) hs2p[w][0][l] = pack2(a0, a1);
                if (hasB) {
                    float b0 = __shfl(nhB, 2 * l), b1 = __shfl(nhB, 2 * l + 1);
                    if (l < 16) hs2p[w][1][l] = pack2(b0, b1);
                }
            }
        }
        float ppA = (l < 32) ? hhA * twr : 0.f;
        #pragma unroll
        for (int o = 32; o; o >>= 1) ppA += __shfl_xor(ppA, o);
        if (l == 0) {
            float prob = sigf(ppA + tb0);
            unsigned long long q = (unsigned long long)llrint((double)prob * 1073741824.0);
            if (q > 0x3FFFFFFFull) q = 0x3FFFFFFFull;
            probq[w][ja] = (unsigned int)q;
        }
        if (hasB) {
            float ppB = (l < 32) ? hhB * twr : 0.f;
            #pragma unroll
            for (int o = 32; o; o >>= 1) ppB += __shfl_xor(ppB, o);
            if (l == 0) {
                float prob = sigf(ppB + tb0);
                unsigned long long q = (unsigned long long)llrint((double)prob * 1073741824.0);
                if (q > 0x3FFFFFFFull) q = 0x3FFFFFFFull;
                probq[w][jb] = (unsigned int)q;
            }
        }
    }
    __syncthreads();
    if (w == 0 && l < ntrig) {
        unsigned int s = probq[0][l] + probq[1][l] + probq[2][l] + probq[3][l];
        atomicAdd(&acc[t0 + l], (unsigned long long)s);   // exact integer, deterministic
    }
}

// ---------------- k3: inline verdict; no-op on no-fire; replay on fire -----
__global__ __launch_bounds__(256, 1) void fin_k(
    const int* __restrict__ seq, const float* __restrict__ memory,
    const float* __restrict__ gwih, const float* __restrict__ gwhh,
    const float* __restrict__ gbhh, const float* __restrict__ qw,
    const float* __restrict__ qb, const float* __restrict__ kw,
    const float* __restrict__ vw, const float* __restrict__ vb,
    const float* __restrict__ lwih, const float* __restrict__ lwhh,
    const float* __restrict__ lbih, const float* __restrict__ lbhh,
    const float* __restrict__ tw, const float* __restrict__ tb,
    const float* __restrict__ hw, const float* __restrict__ hb,
    float* __restrict__ ws, float* __restrict__ out)
{
    int tid = threadIdx.x, w = tid >> 6, l = tid & 63, b = blockIdx.x;
    const unsigned long long* acc = (const unsigned long long*)(ws + OFF_ACC);

    // ---- inline verdict from exact sums (trig_k complete: stream order) ----
    __shared__ int redmin[4];
    {
        int mymin = 1 << 30;
        if (tid >= 3 && acc[tid] > THRESH30) mymin = tid;
        #pragma unroll
        for (int o = 32; o; o >>= 1) mymin = min(mymin, __shfl_xor(mymin, o));
        if (l == 0) redmin[w] = mymin;
    }
    __syncthreads();
    int tc = min(min(redmin[0], redmin[1]), min(redmin[2], redmin[3]));
    if (tc > 255) {
        if (b == 0 && tid == 0) out[65536] = 0.f;
        return;                         // common path
    }

    int r = b * 4 + w;
    const float* tokproj = ws + OFF_TOKPROJ;
    unsigned int* S2 = (unsigned int*)(ws + OFF_SLOT2);

    __shared__ float hs[4][64], qs[4][64], us[4][64], rs[4][64];
    __shared__ float hs2f[4][32];
    __shared__ float PXl[4][4][128];
    __shared__ unsigned int probq[4];
    __shared__ int flagLds;
    __shared__ int toks[4][256];

    for (int k = 0; k < 4; ++k) toks[w][k * 64 + l] = seq[r * 256 + k * 64 + l];
    if (tid == 0) flagLds = 0;

    float wh0[64], wh1[64], wh2[64], wl0[64], wl1[64], lh0[32], lh1[32];
    #pragma unroll
    for (int d4 = 0; d4 < 16; ++d4) {
        float4 a0 = *(const float4*)(gwhh + (size_t)l * 64 + d4 * 4);
        float4 a1 = *(const float4*)(gwhh + (size_t)(64 + l) * 64 + d4 * 4);
        float4 a2 = *(const float4*)(gwhh + (size_t)(128 + l) * 64 + d4 * 4);
        float4 b0 = *(const float4*)(lwih + (size_t)l * 64 + d4 * 4);
        float4 b1 = *(const float4*)(lwih + (size_t)(64 + l) * 64 + d4 * 4);
        wh0[d4*4] = a0.x; wh0[d4*4+1] = a0.y; wh0[d4*4+2] = a0.z; wh0[d4*4+3] = a0.w;
        wh1[d4*4] = a1.x; wh1[d4*4+1] = a1.y; wh1[d4*4+2] = a1.z; wh1[d4*4+3] = a1.w;
        wh2[d4*4] = a2.x; wh2[d4*4+1] = a2.y; wh2[d4*4+2] = a2.z; wh2[d4*4+3] = a2.w;
        wl0[d4*4] = b0.x; wl0[d4*4+1] = b0.y; wl0[d4*4+2] = b0.z; wl0[d4*4+3] = b0.w;
        wl1[d4*4] = b1.x; wl1[d4*4+1] = b1.y; wl1[d4*4+2] = b1.z; wl1[d4*4+3] = b1.w;
    }
    #pragma unroll
    for (int d4 = 0; d4 < 8; ++d4) {
        float4 c0 = *(const float4*)(lwhh + (size_t)l * 32 + d4 * 4);
        float4 c1 = *(const float4*)(lwhh + (size_t)(64 + l) * 32 + d4 * 4);
        lh0[d4*4] = c0.x; lh0[d4*4+1] = c0.y; lh0[d4*4+2] = c0.z; lh0[d4*4+3] = c0.w;
        lh1[d4*4] = c1.x; lh1[d4*4+1] = c1.y; lh1[d4*4+2] = c1.z; lh1[d4*4+3] = c1.w;
    }
    float g0b = gbhh[l], g1b = gbhh[64 + l], g2b = gbhh[128 + l];
    float lb0 = lbih[l] + lbhh[l], lb1 = lbih[64 + l] + lbhh[64 + l];
    float twr = (l < 32) ? tw[l] : 0.f;
    float tb0 = tb[0];
    const float* mrow = memory + (size_t)r * 16384;

    float h = 0.f;
    hs[w][l] = 0.f;
    bool fire = false, brk = false;
    int cnt = 1;
    __syncthreads();

    for (int t = 0; t < 256; ++t) {
        int tok = toks[w][t];
        float gi0 = tokproj[tok * 192 + l], gi1 = tokproj[tok * 192 + 64 + l],
              gi2 = tokproj[tok * 192 + 128 + l];
        float gh0 = g0b, gh1 = g1b, gh2 = g2b;
        #pragma unroll
        for (int d4 = 0; d4 < 16; ++d4) {
            float4 hv = *(const float4*)&hs[w][d4 * 4];
            gh0 += hv.x*wh0[d4*4] + hv.y*wh0[d4*4+1] + hv.z*wh0[d4*4+2] + hv.w*wh0[d4*4+3];
            gh1 += hv.x*wh1[d4*4] + hv.y*wh1[d4*4+1] + hv.z*wh1[d4*4+2] + hv.w*wh1[d4*4+3];
            gh2 += hv.x*wh2[d4*4] + hv.y*wh2[d4*4+1] + hv.z*wh2[d4*4+2] + hv.w*wh2[d4*4+3];
        }
        if (fire) {
            // ---- unfused exact attention on h_{t-1} ----
            float q = qb[l];
            #pragma unroll
            for (int d4 = 0; d4 < 16; ++d4) {
                float4 q4 = *(const float4*)(qw + (size_t)l * 64 + d4 * 4);
                float4 hv = *(const float4*)&hs[w][d4 * 4];
                q += hv.x * q4.x + hv.y * q4.y + hv.z * q4.z + hv.w * q4.w;
            }
            qs[w][l] = q;
            float qk = 0.f;
            for (int e = 0; e < 64; ++e) qk += qs[w][e] * kw[(size_t)e * 64 + l];
            qk *= 0.125f;
            us[w][l] = qk;
            float sc[4];
            for (int k = 0; k < 4; ++k) {
                const float* mp = mrow + (size_t)(k * 64 + l) * 64;
                float s = 0.f;
                #pragma unroll
                for (int d4 = 0; d4 < 16; ++d4) {
                    float4 m4 = *(const float4*)(mp + d4 * 4);
                    float4 kv = *(const float4*)&us[w][d4 * 4];
                    s += m4.x * kv.x + m4.y * kv.y + m4.z * kv.z + m4.w * kv.w;
                }
                sc[k] = s;
            }
            float mx = fmaxf(fmaxf(sc[0], sc[1]), fmaxf(sc[2], sc[3]));
            for (int o = 32; o; o >>= 1) mx = fmaxf(mx, __shfl_xor(mx, o));
            float den = 0.f;
            #pragma unroll
            for (int k = 0; k < 4; ++k) { sc[k] = expf(sc[k] - mx); den += sc[k]; }
            for (int o = 32; o; o >>= 1) den += __shfl_xor(den, o);
            float u = 0.f;
            for (int m = 0; m < 256; ++m) {
                float wm = __shfl(sc[m >> 6], m & 63);
                u += wm * mrow[(size_t)m * 64 + l];
            }
            u /= den;
            us[w][l] = u;
            float ret = vb[l];
            #pragma unroll
            for (int d4 = 0; d4 < 16; ++d4) {
                float4 v4 = *(const float4*)(vw + (size_t)l * 64 + d4 * 4);
                float4 uv = *(const float4*)&us[w][d4 * 4];
                ret += uv.x * v4.x + uv.y * v4.y + uv.z * v4.z + uv.w * v4.w;
            }
            rs[w][l] = ret;
            for (int e = 0; e < 64; ++e) {
                float re = rs[w][e];
                gi0 += re * gwih[(size_t)l * 128 + 64 + e];
                gi1 += re * gwih[(size_t)(64 + l) * 128 + 64 + e];
                gi2 += re * gwih[(size_t)(128 + l) * 128 + 64 + e];
            }
        }
        fire = false;
        float r_ = sigf(gi0 + gh0), z_ = sigf(gi1 + gh1);
        float n_ = tanhf_fast(gi2 + r_ * gh2);
        h = (1.f - z_) * n_ + z_ * h;
        hs[w][l] = h;

        float p0 = lb0, p1 = lb1;
        #pragma unroll
        for (int d4 = 0; d4 < 16; ++d4) {
            float4 hv = *(const float4*)&hs[w][d4 * 4];
            p0 += hv.x*wl0[d4*4] + hv.y*wl0[d4*4+1] + hv.z*wl0[d4*4+2] + hv.w*wl0[d4*4+3];
            p1 += hv.x*wl1[d4*4] + hv.y*wl1[d4*4+1] + hv.z*wl1[d4*4+2] + hv.w*wl1[d4*4+3];
        }
        PXl[w][t & 3][l] = p0; PXl[w][t & 3][64 + l] = p1;

        if (t == tc) {
            fire = true;
        } else if (t > tc) {
            float hh = 0.f, cc = 0.f;
            #pragma unroll
            for (int k = 0; k < 4; ++k) {
                int s2 = (t - 3 + k) & 3;
                float q0 = PXl[w][s2][l], q1 = PXl[w][s2][64 + l];
                if (k) {
                    #pragma unroll
                    for (int d4 = 0; d4 < 8; ++d4) {
                        float4 hv = *(const float4*)&hs2f[w][d4 * 4];
                        q0 += hv.x*lh0[d4*4] + hv.y*lh0[d4*4+1] + hv.z*lh0[d4*4+2] + hv.w*lh0[d4*4+3];
                        q1 += hv.x*lh1[d4*4] + hv.y*lh1[d4*4+1] + hv.z*lh1[d4*4+2] + hv.w*lh1[d4*4+3];
                    }
                }
                float f_ = __shfl(q0, l + 32), o_ = __shfl(q1, l + 32);
                float ig = sigf(q0), ff = sigf(f_), gg = tanhf_fast(q1), oo = sigf(o_);
                float ncc = ff * cc + ig * gg;
                float nhh = oo * tanhf_fast(ncc);
                if (l < 32) { cc = ncc; hh = nhh; hs2f[w][l] = nhh; }
            }
            float pp = (l < 32) ? hh * twr : 0.f;
            #pragma unroll
            for (int o = 32; o; o >>= 1) pp += __shfl_xor(pp, o);
            if (l == 0) {
                float prob = sigf(pp + tb0);
                unsigned long long q = (unsigned long long)llrint((double)prob * 134217728.0);
                if (q > 0x7FFFFFFull) q = 0x7FFFFFFull;
                probq[w] = (unsigned int)q;
            }
            __syncthreads();
            if (w == 0 && l == 0) {
                unsigned int s = probq[0] + probq[1] + probq[2] + probq[3];
                __hip_atomic_store(&S2[(size_t)t * 256 + b], (1u << 30) | s,
                                   __ATOMIC_RELAXED, __HIP_MEMORY_SCOPE_AGENT);
            }
            if (w == 0) {
                unsigned long long tot = 0; int spin = 0; bool ok = true;
                if (!brk) {
                    for (;;) {
                        bool all4 = true; tot = 0;
                        #pragma unroll
                        for (int k2 = 0; k2 < 4; ++k2) {
                            unsigned int v = __hip_atomic_load(&S2[(size_t)t * 256 + k2 * 64 + l],
                                                               __ATOMIC_RELAXED, __HIP_MEMORY_SCOPE_AGENT);
                            all4 &= ((v >> 30) == 1u);
                            tot += (v & 0x3FFFFFFFu);
                        }
                        if (__all(all4)) break;
                        if (++spin > SPIN_BOUND) { ok = false; brk = true; break; }
                        __builtin_amdgcn_s_sleep(1);
                    }
                } else ok = false;
                #pragma unroll
                for (int o = 32; o; o >>= 1) tot += __shfl_xor(tot, o);
                int dec = (ok && tot > THRESH27) ? 1 : 0;
                cnt += dec;
                if (l == 0) flagLds = dec;
            }
            __syncthreads();
            fire = (flagLds != 0);
        }
    }

    // overwrite logits from exact replayed h
    float sL = hb[l];
    #pragma unroll
    for (int d4 = 0; d4 < 16; ++d4) {
        float4 w4 = *(const float4*)(hw + (size_t)l * 64 + d4 * 4);
        float4 hv = *(const float4*)&hs[w][d4 * 4];
        sL += hv.x * w4.x + hv.y * w4.y + hv.z * w4.z + hv.w * w4.w;
    }
    out[r * 64 + l] = sL;
    if (b == 0 && w == 0 && l == 0)
        out[65536] = brk ? -1234.f : (float)cnt / 256.f;
}

extern "C" void kernel_launch(void* const* d_in, const int* in_sizes, int n_in,
                              void* d_out, int out_size, void* d_ws, size_t ws_size,
                              hipStream_t stream)
{
    const int*   seq    = (const int*)d_in[0];
    const float* memory = (const float*)d_in[1];
    const float* embed  = (const float*)d_in[2];
    const float* gwih   = (const float*)d_in[3];
    const float* gwhh   = (const float*)d_in[4];
    const float* gbih   = (const float*)d_in[5];
    const float* gbhh   = (const float*)d_in[6];
    const float* qw     = (const float*)d_in[7];
    const float* qb     = (const float*)d_in[8];
    const float* kw     = (const float*)d_in[9];
    // d_in[10] = k_b : cancels in softmax, unused
    const float* vw     = (const float*)d_in[11];
    const float* vb     = (const float*)d_in[12];
    const float* lwih   = (const float*)d_in[13];
    const float* lwhh   = (const float*)d_in[14];
    const float* lbih   = (const float*)d_in[15];
    const float* lbhh   = (const float*)d_in[16];
    const float* tw     = (const float*)d_in[17];
    const float* tb     = (const float*)d_in[18];
    const float* hw     = (const float*)d_in[19];
    const float* hb     = (const float*)d_in[20];
    float* ws = (float*)d_ws;
    float* out = (float*)d_out;

    prep_k<<<81, 64, 0, stream>>>(embed, gwih, gbih, ws);
    gru_k<<<256, 256, 0, stream>>>(seq, gwhh, gbhh, hw, hb, ws, out);
    trig_k<<<4096, 256, 0, stream>>>(lwih, lwhh, lbih, lbhh, tw, tb, ws);
    fin_k<<<256, 256, 0, stream>>>(seq, memory, gwih, gwhh, gbhh, qw, qb, kw,
                                   vw, vb, lwih, lwhh, lbih, lbhh, tw, tb,
                                   hw, hb, ws, out);
}

// Round 14
// 511.902 us; speedup vs baseline: 4.3941x; 1.1579x over previous
//
#include <hip/hip_runtime.h>
#include <hip/hip_fp16.h>
#include <math.h>

// ws float offsets
#define OFF_TOKPROJ 0         // 12288 floats
#define OFF_ACC     12288     // 256 u64 = 512 floats (exact q30 prob sums)
#define OFF_SLOT2   12800     // 256*256 u32 (rare path, tagged q27 sums)
#define OFF_HH      78336     // 1024*256*64 fp16 = 8388608 floats
// total = 8,466,944 floats = 33.87 MB

#define THRESH30 (512ULL << 30)
#define THRESH27 (512ULL << 27)
#define SPIN_BOUND (1 << 18)

// fast transcendentals: v_exp_f32 + fast rcp (~2 ulp)
__device__ __forceinline__ float sigf(float x) {
    return __fdividef(1.f, 1.f + __expf(-x));
}
__device__ __forceinline__ float tanhf_fast(float x) {
    float e2 = __expf(-2.f * fabsf(x));
    float r = __fdividef(1.f - e2, 1.f + e2);           // >= 0
    return __uint_as_float(__float_as_uint(r) | (__float_as_uint(x) & 0x80000000u));
}

__device__ __forceinline__ unsigned int pack2(float x, float y) {
    union { unsigned int u; _Float16 h[2]; } v;
    v.h[0] = (_Float16)x; v.h[1] = (_Float16)y;
    return v.u;
}
__device__ __forceinline__ float unplo(unsigned int u) {
    union { unsigned int x; _Float16 h[2]; } v; v.x = u; return (float)v.h[0];
}
__device__ __forceinline__ float unphi(unsigned int u) {
    union { unsigned int x; _Float16 h[2]; } v; v.x = u; return (float)v.h[1];
}
__device__ __forceinline__ float dot2acc(unsigned int a, unsigned int b, float acc) {
#if __has_builtin(__builtin_amdgcn_fdot2)
    typedef _Float16 hf2 __attribute__((ext_vector_type(2)));
    union { unsigned int u; hf2 h; } ua, ub;
    ua.u = a; ub.u = b;
    return __builtin_amdgcn_fdot2(ua.h, ub.h, acc, false);
#else
    union { unsigned int u; _Float16 h[2]; } ua, ub;
    ua.u = a; ub.u = b;
    return acc + (float)ua.h[0] * (float)ub.h[0] + (float)ua.h[1] * (float)ub.h[1];
#endif
}

// ---------------- prep: tokproj table + zero ACC/SLOT2 ----------------
__global__ __launch_bounds__(64) void prep_k(
    const float* __restrict__ embed, const float* __restrict__ gwih,
    const float* __restrict__ gbih, float* __restrict__ ws)
{
    int blk = blockIdx.x, l = threadIdx.x;
    if (blk < 64) {
        float* tokproj = ws + OFF_TOKPROJ;
        int v = blk;
        for (int j = l; j < 192; j += 64) {
            float s = gbih[j];
            for (int d = 0; d < 64; ++d) s += embed[v * 64 + d] * gwih[j * 128 + d];
            tokproj[v * 192 + j] = s;
        }
    } else {
        float* z = ws + OFF_ACC;
        int base = (blk - 64) * 4096;
        int end = 512 + 65536;
        for (int i = base + l; i < base + 4096; i += 64)
            if (i < end) z[i] = 0.f;
    }
}

// ---------------- k1: GRU-only recurrence + fp16 history + logits ----------
__global__ __launch_bounds__(256, 1) void gru_k(
    const int* __restrict__ seq, const float* __restrict__ gwhh,
    const float* __restrict__ gbhh, const float* __restrict__ hw,
    const float* __restrict__ hb, float* __restrict__ ws,
    float* __restrict__ out)
{
    int tid = threadIdx.x, w = tid >> 6, l = tid & 63, b = blockIdx.x;
    int r = b * 4 + w;
    const float* tokproj = ws + OFF_TOKPROJ;
    __half* Hh = (__half*)(ws + OFF_HH);

    __shared__ float hs[4][64];
    __shared__ int toks[4][256];
    for (int k = 0; k < 4; ++k) toks[w][k * 64 + l] = seq[r * 256 + k * 64 + l];

    float wh0[64], wh1[64], wh2[64];
    #pragma unroll
    for (int d4 = 0; d4 < 16; ++d4) {
        float4 a0 = *(const float4*)(gwhh + (size_t)l * 64 + d4 * 4);
        float4 a1 = *(const float4*)(gwhh + (size_t)(64 + l) * 64 + d4 * 4);
        float4 a2 = *(const float4*)(gwhh + (size_t)(128 + l) * 64 + d4 * 4);
        wh0[d4*4] = a0.x; wh0[d4*4+1] = a0.y; wh0[d4*4+2] = a0.z; wh0[d4*4+3] = a0.w;
        wh1[d4*4] = a1.x; wh1[d4*4+1] = a1.y; wh1[d4*4+2] = a1.z; wh1[d4*4+3] = a1.w;
        wh2[d4*4] = a2.x; wh2[d4*4+1] = a2.y; wh2[d4*4+2] = a2.z; wh2[d4*4+3] = a2.w;
    }
    float g0b = gbhh[l], g1b = gbhh[64 + l], g2b = gbhh[128 + l];

    float h = 0.f;
    hs[w][l] = 0.f;
    int tok0 = toks[w][0];
    float gi0 = tokproj[tok0 * 192 + l], gi1 = tokproj[tok0 * 192 + 64 + l],
          gi2 = tokproj[tok0 * 192 + 128 + l];

    for (int t = 0; t < 256; ++t) {
        float ni0 = 0.f, ni1 = 0.f, ni2 = 0.f;
        if (t < 255) {
            int tk = toks[w][t + 1];
            ni0 = tokproj[tk * 192 + l];
            ni1 = tokproj[tk * 192 + 64 + l];
            ni2 = tokproj[tk * 192 + 128 + l];
        }
        // 4 rotating accumulators per gate: break the serial FMA chain
        float A0[4] = {0.f, 0.f, 0.f, 0.f};
        float A1[4] = {0.f, 0.f, 0.f, 0.f};
        float A2[4] = {0.f, 0.f, 0.f, 0.f};
        #pragma unroll
        for (int d4 = 0; d4 < 16; ++d4) {
            float4 hv = *(const float4*)&hs[w][d4 * 4];
            A0[d4 & 3] += hv.x*wh0[d4*4] + hv.y*wh0[d4*4+1] + hv.z*wh0[d4*4+2] + hv.w*wh0[d4*4+3];
            A1[d4 & 3] += hv.x*wh1[d4*4] + hv.y*wh1[d4*4+1] + hv.z*wh1[d4*4+2] + hv.w*wh1[d4*4+3];
            A2[d4 & 3] += hv.x*wh2[d4*4] + hv.y*wh2[d4*4+1] + hv.z*wh2[d4*4+2] + hv.w*wh2[d4*4+3];
        }
        float gh0 = g0b + ((A0[0] + A0[1]) + (A0[2] + A0[3]));
        float gh1 = g1b + ((A1[0] + A1[1]) + (A1[2] + A1[3]));
        float gh2 = g2b + ((A2[0] + A2[1]) + (A2[2] + A2[3]));
        float r_ = sigf(gi0 + gh0), z_ = sigf(gi1 + gh1);
        float n_ = tanhf_fast(gi2 + r_ * gh2);
        h = (1.f - z_) * n_ + z_ * h;
        hs[w][l] = h;
        Hh[((size_t)r * 256 + t) * 64 + l] = __float2half(h);
        gi0 = ni0; gi1 = ni1; gi2 = ni2;
    }

    // logits from exact h_255
    float sL = hb[l];
    #pragma unroll
    for (int d4 = 0; d4 < 16; ++d4) {
        float4 w4 = *(const float4*)(hw + (size_t)l * 64 + d4 * 4);
        float4 hv = *(const float4*)&hs[w][d4 * 4];
        sL += hv.x * w4.x + hv.y * w4.y + hv.z * w4.z + hv.w * w4.w;
    }
    out[r * 64 + l] = sL;
}

// ---------------- k2: all triggers; packed fp16 LDS + dot2; 4 blocks/CU ----
__global__ __launch_bounds__(256, 4) void trig_k(
    const float* __restrict__ lwih, const float* __restrict__ lwhh,
    const float* __restrict__ lbih, const float* __restrict__ lbhh,
    const float* __restrict__ tw, const float* __restrict__ tb,
    float* __restrict__ ws)
{
    int tid = threadIdx.x, w = tid >> 6, l = tid & 63, b = blockIdx.x;
    int rg = b >> 4, c = b & 15;
    int r = rg * 4 + w;
    int t0 = 3 + 16 * c;
    int ntrig = (c == 15) ? 13 : 16;
    int wlen = ntrig + 3;

    const unsigned int* HhU = (const unsigned int*)(ws + OFF_HH);
    unsigned long long* acc = (unsigned long long*)(ws + OFF_ACC);

    __shared__ unsigned int hwin2[4][608];     // 19 x 32 half2 per wave
    __shared__ unsigned int pwinp[4][19][64];  // packed (p0,p1) fp16x2
    __shared__ unsigned int hs2p[4][2][16];    // packed LSTM hidden (A,B chains)
    __shared__ unsigned int probq[4][16];

    // ---- packed weights in registers: 96 VGPRs ----
    unsigned int wl0h[32], wl1h[32], lh0h[16], lh1h[16];
    #pragma unroll
    for (int d2 = 0; d2 < 32; ++d2) {
        wl0h[d2] = pack2(lwih[(size_t)l * 64 + 2*d2], lwih[(size_t)l * 64 + 2*d2 + 1]);
        wl1h[d2] = pack2(lwih[(size_t)(64 + l) * 64 + 2*d2], lwih[(size_t)(64 + l) * 64 + 2*d2 + 1]);
    }
    #pragma unroll
    for (int d2 = 0; d2 < 16; ++d2) {
        lh0h[d2] = pack2(lwhh[(size_t)l * 32 + 2*d2], lwhh[(size_t)l * 32 + 2*d2 + 1]);
        lh1h[d2] = pack2(lwhh[(size_t)(64 + l) * 32 + 2*d2], lwhh[(size_t)(64 + l) * 32 + 2*d2 + 1]);
    }
    float lb0 = lbih[l] + lbhh[l], lb1 = lbih[64 + l] + lbhh[64 + l];
    float twr = (l < 32) ? tw[l] : 0.f;
    float tb0 = tb[0];

    // ---- stage packed h window ----
    for (int idx = l; idx < wlen * 32; idx += 64)
        hwin2[w][idx] = HhU[((size_t)r * 256 + (t0 - 3)) * 32 + idx];

    // ---- projections via fdot2, packed store ----
    for (int i = 0; i < wlen; ++i) {
        float p0 = lb0, p1 = lb1;
        #pragma unroll
        for (int d8 = 0; d8 < 8; ++d8) {
            uint4 hv = *(const uint4*)&hwin2[w][i * 32 + d8 * 4];
            p0 = dot2acc(hv.x, wl0h[d8*4+0], p0); p1 = dot2acc(hv.x, wl1h[d8*4+0], p1);
            p0 = dot2acc(hv.y, wl0h[d8*4+1], p0); p1 = dot2acc(hv.y, wl1h[d8*4+1], p1);
            p0 = dot2acc(hv.z, wl0h[d8*4+2], p0); p1 = dot2acc(hv.z, wl1h[d8*4+2], p1);
            p0 = dot2acc(hv.w, wl0h[d8*4+3], p0); p1 = dot2acc(hv.w, wl1h[d8*4+3], p1);
        }
        pwinp[w][i][l] = pack2(p0, p1);
    }

    // ---- triggers: 2 independent LSTM chains interleaved (j, j+8) ----
    for (int jp = 0; jp < 8 && jp < ntrig; ++jp) {
        int ja = jp, jb = jp + 8;
        bool hasB = (jb < ntrig);
        float hhA = 0.f, ccA = 0.f, hhB = 0.f, ccB = 0.f;
        #pragma unroll
        for (int k = 0; k < 4; ++k) {
            unsigned int uA = pwinp[w][ja + k][l];
            float q0A = unplo(uA), q1A = unphi(uA);
            float q0B = 0.f, q1B = 0.f;
            if (hasB) {
                unsigned int uB = pwinp[w][jb + k][l];
                q0B = unplo(uB); q1B = unphi(uB);
            }
            if (k) {
                #pragma unroll
                for (int d4 = 0; d4 < 4; ++d4) {
                    uint4 ha = *(const uint4*)&hs2p[w][0][d4 * 4];
                    q0A = dot2acc(ha.x, lh0h[d4*4+0], q0A); q1A = dot2acc(ha.x, lh1h[d4*4+0], q1A);
                    q0A = dot2acc(ha.y, lh0h[d4*4+1], q0A); q1A = dot2acc(ha.y, lh1h[d4*4+1], q1A);
                    q0A = dot2acc(ha.z, lh0h[d4*4+2], q0A); q1A = dot2acc(ha.z, lh1h[d4*4+2], q1A);
                    q0A = dot2acc(ha.w, lh0h[d4*4+3], q0A); q1A = dot2acc(ha.w, lh1h[d4*4+3], q1A);
                }
                if (hasB) {
                    #pragma unroll
                    for (int d4 = 0; d4 < 4; ++d4) {
                        uint4 hb2 = *(const uint4*)&hs2p[w][1][d4 * 4];
                        q0B = dot2acc(hb2.x, lh0h[d4*4+0], q0B); q1B = dot2acc(hb2.x, lh1h[d4*4+0], q1B);
                        q0B = dot2acc(hb2.y, lh0h[d4*4+1], q0B); q1B = dot2acc(hb2.y, lh1h[d4*4+1], q1B);
                        q0B = dot2acc(hb2.z, lh0h[d4*4+2], q0B); q1B = dot2acc(hb2.z, lh1h[d4*4+2], q1B);
                        q0B = dot2acc(hb2.w, lh0h[d4*4+3], q0B); q1B = dot2acc(hb2.w, lh1h[d4*4+3], q1B);
                    }
                }
            }
            // A: sig before shuffle (one sigf serves i and f)
            float s0A = sigf(q0A);               // low: i, high: f
            float t1A = tanhf_fast(q1A);         // low: g
            float s1A = sigf(q1A);               // high: o
            float ffA = __shfl(s0A, l + 32);
            float ooA = __shfl(s1A, l + 32);
            float nccA = ffA * ccA + s0A * t1A;
            float nhA = ooA * tanhf_fast(nccA);
            if (l < 32) { ccA = nccA; hhA = nhA; }
            float nhB = 0.f;
            if (hasB) {
                float s0B = sigf(q0B);
                float t1B = tanhf_fast(q1B);
                float s1B = sigf(q1B);
                float ffB = __shfl(s0B, l + 32);
                float ooB = __shfl(s1B, l + 32);
                float nccB = ffB * ccB + s0B * t1B;
                nhB = ooB * tanhf_fast(nccB);
                if (l < 32) { ccB = nccB; hhB = nhB; }
            }
            if (k < 3) {
                float a0 = __shfl(nhA, 2 * l), a1 = __shfl(nhA, 2 * l + 1);
                if (l < 16) hs2p[w][0][l] = pack2(a0, a1);
                if (hasB) {
                    float b0 = __shfl(nhB, 2 * l), b1 = __shfl(nhB, 2 * l + 1);
                    if (l < 16) hs2p[w][1][l] = pack2(b0, b1);
                }
            }
        }
        float ppA = (l < 32) ? hhA * twr : 0.f;
        #pragma unroll
        for (int o = 32; o; o >>= 1) ppA += __shfl_xor(ppA, o);
        if (l == 0) {
            float prob = sigf(ppA + tb0);
            unsigned long long q = (unsigned long long)llrint((double)prob * 1073741824.0);
            if (q > 0x3FFFFFFFull) q = 0x3FFFFFFFull;
            probq[w][ja] = (unsigned int)q;
        }
        if (hasB) {
            float ppB = (l < 32) ? hhB * twr : 0.f;
            #pragma unroll
            for (int o = 32; o; o >>= 1) ppB += __shfl_xor(ppB, o);
            if (l == 0) {
                float prob = sigf(ppB + tb0);
                unsigned long long q = (unsigned long long)llrint((double)prob * 1073741824.0);
                if (q > 0x3FFFFFFFull) q = 0x3FFFFFFFull;
                probq[w][jb] = (unsigned int)q;
            }
        }
    }
    __syncthreads();
    if (w == 0 && l < ntrig) {
        unsigned int s = probq[0][l] + probq[1][l] + probq[2][l] + probq[3][l];
        atomicAdd(&acc[t0 + l], (unsigned long long)s);   // exact integer, deterministic
    }
}

// ---------------- k3: inline verdict; no-op on no-fire; replay on fire -----
__global__ __launch_bounds__(256, 1) void fin_k(
    const int* __restrict__ seq, const float* __restrict__ memory,
    const float* __restrict__ gwih, const float* __restrict__ gwhh,
    const float* __restrict__ gbhh, const float* __restrict__ qw,
    const float* __restrict__ qb, const float* __restrict__ kw,
    const float* __restrict__ vw, const float* __restrict__ vb,
    const float* __restrict__ lwih, const float* __restrict__ lwhh,
    const float* __restrict__ lbih, const float* __restrict__ lbhh,
    const float* __restrict__ tw, const float* __restrict__ tb,
    const float* __restrict__ hw, const float* __restrict__ hb,
    float* __restrict__ ws, float* __restrict__ out)
{
    int tid = threadIdx.x, w = tid >> 6, l = tid & 63, b = blockIdx.x;
    const unsigned long long* acc = (const unsigned long long*)(ws + OFF_ACC);

    // ---- inline verdict from exact sums (trig_k complete: stream order) ----
    __shared__ int redmin[4];
    {
        int mymin = 1 << 30;
        if (tid >= 3 && acc[tid] > THRESH30) mymin = tid;
        #pragma unroll
        for (int o = 32; o; o >>= 1) mymin = min(mymin, __shfl_xor(mymin, o));
        if (l == 0) redmin[w] = mymin;
    }
    __syncthreads();
    int tc = min(min(redmin[0], redmin[1]), min(redmin[2], redmin[3]));
    if (tc > 255) {
        if (b == 0 && tid == 0) out[65536] = 0.f;
        return;                         // common path
    }

    int r = b * 4 + w;
    const float* tokproj = ws + OFF_TOKPROJ;
    unsigned int* S2 = (unsigned int*)(ws + OFF_SLOT2);

    __shared__ float hs[4][64], qs[4][64], us[4][64], rs[4][64];
    __shared__ float hs2f[4][32];
    __shared__ float PXl[4][4][128];
    __shared__ unsigned int probq[4];
    __shared__ int flagLds;
    __shared__ int toks[4][256];

    for (int k = 0; k < 4; ++k) toks[w][k * 64 + l] = seq[r * 256 + k * 64 + l];
    if (tid == 0) flagLds = 0;

    float wh0[64], wh1[64], wh2[64], wl0[64], wl1[64], lh0[32], lh1[32];
    #pragma unroll
    for (int d4 = 0; d4 < 16; ++d4) {
        float4 a0 = *(const float4*)(gwhh + (size_t)l * 64 + d4 * 4);
        float4 a1 = *(const float4*)(gwhh + (size_t)(64 + l) * 64 + d4 * 4);
        float4 a2 = *(const float4*)(gwhh + (size_t)(128 + l) * 64 + d4 * 4);
        float4 b0 = *(const float4*)(lwih + (size_t)l * 64 + d4 * 4);
        float4 b1 = *(const float4*)(lwih + (size_t)(64 + l) * 64 + d4 * 4);
        wh0[d4*4] = a0.x; wh0[d4*4+1] = a0.y; wh0[d4*4+2] = a0.z; wh0[d4*4+3] = a0.w;
        wh1[d4*4] = a1.x; wh1[d4*4+1] = a1.y; wh1[d4*4+2] = a1.z; wh1[d4*4+3] = a1.w;
        wh2[d4*4] = a2.x; wh2[d4*4+1] = a2.y; wh2[d4*4+2] = a2.z; wh2[d4*4+3] = a2.w;
        wl0[d4*4] = b0.x; wl0[d4*4+1] = b0.y; wl0[d4*4+2] = b0.z; wl0[d4*4+3] = b0.w;
        wl1[d4*4] = b1.x; wl1[d4*4+1] = b1.y; wl1[d4*4+2] = b1.z; wl1[d4*4+3] = b1.w;
    }
    #pragma unroll
    for (int d4 = 0; d4 < 8; ++d4) {
        float4 c0 = *(const float4*)(lwhh + (size_t)l * 32 + d4 * 4);
        float4 c1 = *(const float4*)(lwhh + (size_t)(64 + l) * 32 + d4 * 4);
        lh0[d4*4] = c0.x; lh0[d4*4+1] = c0.y; lh0[d4*4+2] = c0.z; lh0[d4*4+3] = c0.w;
        lh1[d4*4] = c1.x; lh1[d4*4+1] = c1.y; lh1[d4*4+2] = c1.z; lh1[d4*4+3] = c1.w;
    }
    float g0b = gbhh[l], g1b = gbhh[64 + l], g2b = gbhh[128 + l];
    float lb0 = lbih[l] + lbhh[l], lb1 = lbih[64 + l] + lbhh[64 + l];
    float twr = (l < 32) ? tw[l] : 0.f;
    float tb0 = tb[0];
    const float* mrow = memory + (size_t)r * 16384;

    float h = 0.f;
    hs[w][l] = 0.f;
    bool fire = false, brk = false;
    int cnt = 1;
    __syncthreads();

    for (int t = 0; t < 256; ++t) {
        int tok = toks[w][t];
        float gi0 = tokproj[tok * 192 + l], gi1 = tokproj[tok * 192 + 64 + l],
              gi2 = tokproj[tok * 192 + 128 + l];
        float gh0 = g0b, gh1 = g1b, gh2 = g2b;
        #pragma unroll
        for (int d4 = 0; d4 < 16; ++d4) {
            float4 hv = *(const float4*)&hs[w][d4 * 4];
            gh0 += hv.x*wh0[d4*4] + hv.y*wh0[d4*4+1] + hv.z*wh0[d4*4+2] + hv.w*wh0[d4*4+3];
            gh1 += hv.x*wh1[d4*4] + hv.y*wh1[d4*4+1] + hv.z*wh1[d4*4+2] + hv.w*wh1[d4*4+3];
            gh2 += hv.x*wh2[d4*4] + hv.y*wh2[d4*4+1] + hv.z*wh2[d4*4+2] + hv.w*wh2[d4*4+3];
        }
        if (fire) {
            // ---- unfused exact attention on h_{t-1} ----
            float q = qb[l];
            #pragma unroll
            for (int d4 = 0; d4 < 16; ++d4) {
                float4 q4 = *(const float4*)(qw + (size_t)l * 64 + d4 * 4);
                float4 hv = *(const float4*)&hs[w][d4 * 4];
                q += hv.x * q4.x + hv.y * q4.y + hv.z * q4.z + hv.w * q4.w;
            }
            qs[w][l] = q;
            float qk = 0.f;
            for (int e = 0; e < 64; ++e) qk += qs[w][e] * kw[(size_t)e * 64 + l];
            qk *= 0.125f;
            us[w][l] = qk;
            float sc[4];
            for (int k = 0; k < 4; ++k) {
                const float* mp = mrow + (size_t)(k * 64 + l) * 64;
                float s = 0.f;
                #pragma unroll
                for (int d4 = 0; d4 < 16; ++d4) {
                    float4 m4 = *(const float4*)(mp + d4 * 4);
                    float4 kv = *(const float4*)&us[w][d4 * 4];
                    s += m4.x * kv.x + m4.y * kv.y + m4.z * kv.z + m4.w * kv.w;
                }
                sc[k] = s;
            }
            float mx = fmaxf(fmaxf(sc[0], sc[1]), fmaxf(sc[2], sc[3]));
            for (int o = 32; o; o >>= 1) mx = fmaxf(mx, __shfl_xor(mx, o));
            float den = 0.f;
            #pragma unroll
            for (int k = 0; k < 4; ++k) { sc[k] = expf(sc[k] - mx); den += sc[k]; }
            for (int o = 32; o; o >>= 1) den += __shfl_xor(den, o);
            float u = 0.f;
            for (int m = 0; m < 256; ++m) {
                float wm = __shfl(sc[m >> 6], m & 63);
                u += wm * mrow[(size_t)m * 64 + l];
            }
            u /= den;
            us[w][l] = u;
            float ret = vb[l];
            #pragma unroll
            for (int d4 = 0; d4 < 16; ++d4) {
                float4 v4 = *(const float4*)(vw + (size_t)l * 64 + d4 * 4);
                float4 uv = *(const float4*)&us[w][d4 * 4];
                ret += uv.x * v4.x + uv.y * v4.y + uv.z * v4.z + uv.w * v4.w;
            }
            rs[w][l] = ret;
            for (int e = 0; e < 64; ++e) {
                float re = rs[w][e];
                gi0 += re * gwih[(size_t)l * 128 + 64 + e];
                gi1 += re * gwih[(size_t)(64 + l) * 128 + 64 + e];
                gi2 += re * gwih[(size_t)(128 + l) * 128 + 64 + e];
            }
        }
        fire = false;
        float r_ = sigf(gi0 + gh0), z_ = sigf(gi1 + gh1);
        float n_ = tanhf_fast(gi2 + r_ * gh2);
        h = (1.f - z_) * n_ + z_ * h;
        hs[w][l] = h;

        float p0 = lb0, p1 = lb1;
        #pragma unroll
        for (int d4 = 0; d4 < 16; ++d4) {
            float4 hv = *(const float4*)&hs[w][d4 * 4];
            p0 += hv.x*wl0[d4*4] + hv.y*wl0[d4*4+1] + hv.z*wl0[d4*4+2] + hv.w*wl0[d4*4+3];
            p1 += hv.x*wl1[d4*4] + hv.y*wl1[d4*4+1] + hv.z*wl1[d4*4+2] + hv.w*wl1[d4*4+3];
        }
        PXl[w][t & 3][l] = p0; PXl[w][t & 3][64 + l] = p1;

        if (t == tc) {
            fire = true;
        } else if (t > tc) {
            float hh = 0.f, cc = 0.f;
            #pragma unroll
            for (int k = 0; k < 4; ++k) {
                int s2 = (t - 3 + k) & 3;
                float q0 = PXl[w][s2][l], q1 = PXl[w][s2][64 + l];
                if (k) {
                    #pragma unroll
                    for (int d4 = 0; d4 < 8; ++d4) {
                        float4 hv = *(const float4*)&hs2f[w][d4 * 4];
                        q0 += hv.x*lh0[d4*4] + hv.y*lh0[d4*4+1] + hv.z*lh0[d4*4+2] + hv.w*lh0[d4*4+3];
                        q1 += hv.x*lh1[d4*4] + hv.y*lh1[d4*4+1] + hv.z*lh1[d4*4+2] + hv.w*lh1[d4*4+3];
                    }
                }
                float f_ = __shfl(q0, l + 32), o_ = __shfl(q1, l + 32);
                float ig = sigf(q0), ff = sigf(f_), gg = tanhf_fast(q1), oo = sigf(o_);
                float ncc = ff * cc + ig * gg;
                float nhh = oo * tanhf_fast(ncc);
                if (l < 32) { cc = ncc; hh = nhh; hs2f[w][l] = nhh; }
            }
            float pp = (l < 32) ? hh * twr : 0.f;
            #pragma unroll
            for (int o = 32; o; o >>= 1) pp += __shfl_xor(pp, o);
            if (l == 0) {
                float prob = sigf(pp + tb0);
                unsigned long long q = (unsigned long long)llrint((double)prob * 134217728.0);
                if (q > 0x7FFFFFFull) q = 0x7FFFFFFull;
                probq[w] = (unsigned int)q;
            }
            __syncthreads();
            if (w == 0 && l == 0) {
                unsigned int s = probq[0] + probq[1] + probq[2] + probq[3];
                __hip_atomic_store(&S2[(size_t)t * 256 + b], (1u << 30) | s,
                                   __ATOMIC_RELAXED, __HIP_MEMORY_SCOPE_AGENT);
            }
            if (w == 0) {
                unsigned long long tot = 0; int spin = 0; bool ok = true;
                if (!brk) {
                    for (;;) {
                        bool all4 = true; tot = 0;
                        #pragma unroll
                        for (int k2 = 0; k2 < 4; ++k2) {
                            unsigned int v = __hip_atomic_load(&S2[(size_t)t * 256 + k2 * 64 + l],
                                                               __ATOMIC_RELAXED, __HIP_MEMORY_SCOPE_AGENT);
                            all4 &= ((v >> 30) == 1u);
                            tot += (v & 0x3FFFFFFFu);
                        }
                        if (__all(all4)) break;
                        if (++spin > SPIN_BOUND) { ok = false; brk = true; break; }
                        __builtin_amdgcn_s_sleep(1);
                    }
                } else ok = false;
                #pragma unroll
                for (int o = 32; o; o >>= 1) tot += __shfl_xor(tot, o);
                int dec = (ok && tot > THRESH27) ? 1 : 0;
                cnt += dec;
                if (l == 0) flagLds = dec;
            }
            __syncthreads();
            fire = (flagLds != 0);
        }
    }

    // overwrite logits from exact replayed h
    float sL = hb[l];
    #pragma unroll
    for (int d4 = 0; d4 < 16; ++d4) {
        float4 w4 = *(const float4*)(hw + (size_t)l * 64 + d4 * 4);
        float4 hv = *(const float4*)&hs[w][d4 * 4];
        sL += hv.x * w4.x + hv.y * w4.y + hv.z * w4.z + hv.w * w4.w;
    }
    out[r * 64 + l] = sL;
    if (b == 0 && w == 0 && l == 0)
        out[65536] = brk ? -1234.f : (float)cnt / 256.f;
}

extern "C" void kernel_launch(void* const* d_in, const int* in_sizes, int n_in,
                              void* d_out, int out_size, void* d_ws, size_t ws_size,
                              hipStream_t stream)
{
    const int*   seq    = (const int*)d_in[0];
    const float* memory = (const float*)d_in[1];
    const float* embed  = (const float*)d_in[2];
    const float* gwih   = (const float*)d_in[3];
    const float* gwhh   = (const float*)d_in[4];
    const float* gbih   = (const float*)d_in[5];
    const float* gbhh   = (const float*)d_in[6];
    const float* qw     = (const float*)d_in[7];
    const float* qb     = (const float*)d_in[8];
    const float* kw     = (const float*)d_in[9];
    // d_in[10] = k_b : cancels in softmax, unused
    const float* vw     = (const float*)d_in[11];
    const float* vb     = (const float*)d_in[12];
    const float* lwih   = (const float*)d_in[13];
    const float* lwhh   = (const float*)d_in[14];
    const float* lbih   = (const float*)d_in[15];
    const float* lbhh   = (const float*)d_in[16];
    const float* tw     = (const float*)d_in[17];
    const float* tb     = (const float*)d_in[18];
    const float* hw     = (const float*)d_in[19];
    const float* hb     = (const float*)d_in[20];
    float* ws = (float*)d_ws;
    float* out = (float*)d_out;

    prep_k<<<81, 64, 0, stream>>>(embed, gwih, gbih, ws);
    gru_k<<<256, 256, 0, stream>>>(seq, gwhh, gbhh, hw, hb, ws, out);
    trig_k<<<4096, 256, 0, stream>>>(lwih, lwhh, lbih, lbhh, tw, tb, ws);
    fin_k<<<256, 256, 0, stream>>>(seq, memory, gwih, gwhh, gbhh, qw, qb, kw,
                                   vw, vb, lwih, lwhh, lbih, lbhh, tw, tb,
                                   hw, hb, ws, out);
}